// Round 6
// baseline (155.270 us; speedup 1.0000x reference)
//
#include <hip/hip_runtime.h>
#include <math.h>

// Problem constants
#define B_   8
#define C_   64
#define O_   64
#define H_   128
#define W_   128
#define HW_  (H_ * W_)
#define KSZ  576            // C_*9 contraction length

typedef _Float16 f16x8 __attribute__((ext_vector_type(8)));
typedef float    f32x4 __attribute__((ext_vector_type(4)));

#define WPM_BYTES (18 * 4 * 64 * 8 * 2)   // 73728
#define WPA_BYTES (18 * 2 * 64 * 8 * 2)   // 36864
#define TB2_      (B_ * HW_ / 128)        // 1024 transpose tiles (128 px x 64 ch)

// ---------------------------------------------------------------------------
// Prep kernel (unchanged — vectorized transpose + weight prepack).
// ---------------------------------------------------------------------------
__global__ __launch_bounds__(256) void prep_kernel(
    const float* __restrict__ x,
    const float* __restrict__ offw, const float* __restrict__ modw,
    const float* __restrict__ wgt,
    _Float16* __restrict__ xT, _Float16* __restrict__ wpM, _Float16* __restrict__ wpA)
{
    const int bi = blockIdx.x;
    if (bi < TB2_) {
        __shared__ _Float16 tile[128 * 68];
        const int tid = threadIdx.x;
        const int b      = bi >> 7;
        const int pxbase = (bi & 127) * 128;

        const int px4   = (tid & 31) * 4;
        const int cbase = tid >> 5;
        const float* __restrict__ xp = x + (size_t)b * C_ * HW_ + pxbase;
#pragma unroll
        for (int r = 0; r < 8; ++r) {
            const int c = cbase + r * 8;
            const f32x4 v = *(const f32x4*)&xp[(size_t)c * HW_ + px4];
#pragma unroll
            for (int i = 0; i < 4; ++i)
                tile[(px4 + i) * 68 + c] = (_Float16)v[i];
        }
        __syncthreads();

        const int px = tid >> 1;
        const int c0 = (tid & 1) * 32;
        f16x8 w[4];
#pragma unroll
        for (int q = 0; q < 4; ++q)
#pragma unroll
            for (int j = 0; j < 8; ++j)
                w[q][j] = tile[px * 68 + c0 + q * 8 + j];
        _Float16* __restrict__ op = xT + ((size_t)b * HW_ + pxbase + px) * 64 + c0;
#pragma unroll
        for (int q = 0; q < 4; ++q)
            *(f16x8*)&op[q * 8] = w[q];
        return;
    }
    const int g = (bi - TB2_) * 256 + threadIdx.x;
    if (g < 18 * 4 * 64) {
        const int s = g >> 8, mt = (g >> 6) & 3, lane = g & 63;
        const int k = s >> 1, cb = (s & 1) * 32;
        const int o  = mt * 16 + (lane & 15);
        const int c0 = cb + (lane >> 4) * 8;
        f16x8 v;
#pragma unroll
        for (int j = 0; j < 8; ++j) v[j] = (_Float16)wgt[o * KSZ + (c0 + j) * 9 + k];
        *(f16x8*)&wpM[(size_t)g * 8] = v;
    } else if (g < 18 * 4 * 64 + 18 * 2 * 64) {
        const int u = g - 18 * 4 * 64;
        const int s = u >> 7, mt = (u >> 6) & 1, lane = u & 63;
        const int k = s >> 1, cb = (s & 1) * 32;
        const int t  = mt * 16 + (lane & 15);
        const int c0 = cb + (lane >> 4) * 8;
        f16x8 v;
#pragma unroll
        for (int j = 0; j < 8; ++j) {
            float w = 0.0f;
            if (t < 18)      w = offw[t * KSZ + (c0 + j) * 9 + k];
            else if (t < 27) w = modw[(t - 18) * KSZ + (c0 + j) * 9 + k];
            v[j] = (_Float16)w;
        }
        *(f16x8*)&wpA[(size_t)u * 8] = v;
    }
}

__device__ __forceinline__ f16x8 splat8(_Float16 h) {
    f16x8 v = {h, h, h, h, h, h, h, h};
    return v;
}

// ---------------------------------------------------------------------------
// Fused main kernel (v6 — v5 with the UB fixed).
// r5 post-mortem: v5 crashed twice, once on a healthy container => kernel
// guilty. Found bug: okm packed 9 taps x 4 corner-flags = 36 bits into a
// 32-bit unsigned; `<<32` / `>>32` are poison/UB in LLVM, licensing the
// optimizer to mangle the fallback guard logic (plausible memory-fault
// mechanism). v6 encodes the flags as int oks[9] (nibble per tap, no
// shifts >3) and y0s[9]/x0s[9] plain arrays (no packing). Also reverts to
// plain __launch_bounds__(256) this round to isolate the other untested
// risk axis (hard VGPR clamp + spill); re-try the clamp later if VGPR>128.
//
// Structure (unchanged from v5):
//   Phase A view: [3][66][64ch] f16 = 25.3KB (rows ho-1..ho+1, zero-padded).
//   Phase B view: [7][70][32ch] f16 = 31.4KB, staged per channel-half h;
//     corner LDS offsets identical for both halves (chunk = lq within
//     half) -> weights/offsets computed once, live across restage barriers.
//   LDS 31.4KB -> up to 5 blocks/CU by LDS; occupancy now VGPR-bound.
// ---------------------------------------------------------------------------
#define AROWS 3
#define ACOLS 66
#define BROWS 7
#define BCOLS 70

#define PP_IDX(t) (((t) & 3) | (((t) >> 4) << 2))
#define PP_SRC(t) ((((t) & 15) >> 2) * 16)

__global__ __launch_bounds__(256) void dcn_main_kernel(
    const _Float16* __restrict__ xT,    // (B, H, W, C) f16
    const _Float16* __restrict__ wpA,   // packed offset/mod weight frags
    const _Float16* __restrict__ wpM,   // packed main weight frags
    const float* __restrict__ offb,     // (18,)
    const float* __restrict__ modb,     // (9,)
    float* __restrict__ out)            // (B, O, H, W)
{
    __shared__ _Float16 win[BROWS * BCOLS * 32];   // 31360 B (union w/ A view)

    const int tid  = threadIdx.x;
    const int lane = tid & 63;
    const int wave = tid >> 6;
    const int lq   = lane >> 4;
    const int ln   = lane & 15;

    const int bi  = blockIdx.x;
    const int b   = bi & 7;             // XCD-pinned batch
    const int r2  = bi >> 3;            // 0..255
    const int ho  = r2 >> 1;
    const int x0b = (r2 & 1) * 64;
    const int pxw = wave * 16 + ln;     // px within half-row, 0..63
    const int wo  = x0b + pxw;          // this lane's output x

    const _Float16* __restrict__ xbT = xT + (size_t)b * HW_ * 64;

    // ---------------- Stage A view: rows ho-1..ho+1, cols x0b-1..x0b+64 ----
    // [3][66][64ch], zero-padded, 16B chunks q 0..7 swizzled by (cx&7).
#pragma unroll
    for (int it = 0; it < 7; ++it) {
        const int e = it * 256 + tid;
        if (e < AROWS * ACOLS * 8) {
            const int r   = e / (ACOLS * 8);
            const int rem = e - r * (ACOLS * 8);
            const int cx  = rem >> 3;
            const int q   = rem & 7;
            const int yr  = ho - 1 + r;
            const int xc  = x0b - 1 + cx;
            f16x8 v = splat8((_Float16)0.0f);
            if (((unsigned)yr < H_) && ((unsigned)xc < W_))
                v = *(const f16x8*)&xbT[((size_t)(yr * W_ + xc)) * 64 + q * 8];
            *(f16x8*)&win[(r * ACOLS + cx) * 64 + ((q ^ (cx & 7)) * 8)] = v;
        }
    }
    __syncthreads();

    // ---------------- Phase A: offset/modulator conv via MFMA (no branches)
    f32x4 accA[2];
#pragma unroll
    for (int mt = 0; mt < 2; ++mt) accA[mt] = (f32x4){0.f, 0.f, 0.f, 0.f};

#pragma unroll
    for (int s = 0; s < 18; ++s) {
        const int k = s >> 1, h = s & 1;
        const int ki = k / 3, kj = k - ki * 3;
        f16x8 afA[2];
#pragma unroll
        for (int mt = 0; mt < 2; ++mt)
            afA[mt] = *(const f16x8*)&wpA[(size_t)((s * 2 + mt) * 64 + lane) * 8];
        const int sx = pxw + kj;             // col rel to x0b-1
        const int chunk = h * 4 + lq;
        const f16x8 bfA = *(const f16x8*)&win[(ki * ACOLS + sx) * 64 + ((chunk ^ (sx & 7)) * 8)];
#pragma unroll
        for (int mt = 0; mt < 2; ++mt)
            accA[mt] = __builtin_amdgcn_mfma_f32_16x16x32_f16(afA[mt], bfA, accA[mt], 0, 0, 0);
    }

    // Params in registers: lane (lq,ln) owns t = mt*16 + lq*4 + r for px ln.
    float pp[8];
#pragma unroll
    for (int mt = 0; mt < 2; ++mt)
#pragma unroll
        for (int r = 0; r < 4; ++r) {
            const int t = mt * 16 + lq * 4 + r;
            const float val = accA[mt][r];
            float o = 0.0f;
            if (t < 18)      o = val + offb[t];
            else if (t < 27) o = 2.0f / (1.0f + expf(-(val + modb[t - 18])));
            pp[mt * 4 + r] = o;
        }

    // ---------------- Phase B precompute (lives across restage barriers) ---
    float w00k[9], w01k[9], w10k[9], w11k[9];
    int   b00k[9], b01k[9], b10k[9], b11k[9];
    int   oks[9];                 // nibble: bit c = corner c of tap k in-window
    int   y0s[9], x0s[9];
#pragma unroll
    for (int k = 0; k < 9; ++k) {
        const int ki = k / 3, kj = k - ki * 3;
        const float dy = __shfl(pp[PP_IDX(2 * k)],     PP_SRC(2 * k) + ln, 64);
        const float dx = __shfl(pp[PP_IDX(2 * k + 1)], PP_SRC(2 * k + 1) + ln, 64);
        const float mk = __shfl(pp[PP_IDX(18 + k)],    PP_SRC(18 + k) + ln, 64);

        const float ys = (float)(ho - 1 + ki) + dy;
        const float xs = (float)(wo - 1 + kj) + dx;
        const float y0f = floorf(ys), x0f = floorf(xs);
        const float wy = ys - y0f, wx = xs - x0f;
        const int y0 = (int)y0f, x0 = (int)x0f;
        y0s[k] = y0; x0s[k] = x0;
        const float wyc = 1.0f - wy, wxc = 1.0f - wx;
        w00k[k] = wyc * wxc * mk;
        w01k[k] = wyc * wx  * mk;
        w10k[k] = wy  * wxc * mk;
        w11k[k] = wy  * wx  * mk;

        const int sy0 = y0 - ho + 3, sy1 = sy0 + 1;
        const int sx0 = x0 - x0b + 3, sx1 = sx0 + 1;
        const int oy0 = (unsigned)sy0 < BROWS, oy1 = (unsigned)sy1 < BROWS;
        const int ox0 = (unsigned)sx0 < BCOLS, ox1 = (unsigned)sx1 < BCOLS;
        const int ok00 = oy0 & ox0, ok01 = oy0 & ox1;
        const int ok10 = oy1 & ox0, ok11 = oy1 & ox1;
        oks[k] = ok00 | (ok01 << 1) | (ok10 << 2) | (ok11 << 3);
        // 32ch cell = 64B; chunk = lq (same for both halves), swz by (sx&3)
        const int e00 = ((sy0 * BCOLS + sx0) * 32) + ((lq ^ (sx0 & 3)) * 8);
        const int e01 = ((sy0 * BCOLS + sx1) * 32) + ((lq ^ (sx1 & 3)) * 8);
        const int e10 = ((sy1 * BCOLS + sx0) * 32) + ((lq ^ (sx0 & 3)) * 8);
        const int e11 = ((sy1 * BCOLS + sx1) * 32) + ((lq ^ (sx1 & 3)) * 8);
        b00k[k] = ok00 ? e00 : 0;
        b01k[k] = ok01 ? e01 : 0;
        b10k[k] = ok10 ? e10 : 0;
        b11k[k] = ok11 ? e11 : 0;
    }

    // ---------------- Phase B: two channel-half passes ---------------------
    f32x4 acc[4];
#pragma unroll
    for (int mt = 0; mt < 4; ++mt) acc[mt] = (f32x4){0.f, 0.f, 0.f, 0.f};

#pragma unroll
    for (int h = 0; h < 2; ++h) {
        const int cb = h * 32;
        __syncthreads();   // previous window consumers done
        // stage B view: [7][70][32ch] half h, rows ho-3.., cols x0b-3..
#pragma unroll
        for (int it = 0; it < 8; ++it) {
            const int e = it * 256 + tid;
            if (e < BROWS * BCOLS * 4) {
                const int r   = e / (BCOLS * 4);
                const int rem = e - r * (BCOLS * 4);
                const int cx  = rem >> 2;
                const int q   = rem & 3;
                const int yr  = ho - 3 + r;
                const int xc  = x0b - 3 + cx;
                f16x8 v = splat8((_Float16)0.0f);
                if (((unsigned)yr < H_) && ((unsigned)xc < W_))
                    v = *(const f16x8*)&xbT[((size_t)(yr * W_ + xc)) * 64 + cb + q * 8];
                *(f16x8*)&win[(r * BCOLS + cx) * 32 + ((q ^ (cx & 3)) * 8)] = v;
            }
        }
        __syncthreads();

        const int c0 = cb + lq * 8;   // fallback channel base
#pragma unroll
        for (int k = 0; k < 9; ++k) {
            const int s = 2 * k + h;

            f16x8 af[4];
#pragma unroll
            for (int mt = 0; mt < 4; ++mt)
                af[mt] = *(const f16x8*)&wpM[(size_t)((s * 4 + mt) * 64 + lane) * 8];

            f16x8 a00 = *(const f16x8*)&win[b00k[k]];
            f16x8 a01 = *(const f16x8*)&win[b01k[k]];
            f16x8 a10 = *(const f16x8*)&win[b10k[k]];
            f16x8 a11 = *(const f16x8*)&win[b11k[k]];

            // rare fallback: corner outside window (value zeroed if off-image)
            const int okk = oks[k];
            if (__builtin_expect(okk != 15, 0)) {
                const int y0 = y0s[k], x0 = x0s[k];
                if (!(okk & 1)) {
                    const int yc = min(max(y0, 0), H_ - 1), xc = min(max(x0, 0), W_ - 1);
                    const bool in = ((unsigned)y0 < H_) && ((unsigned)x0 < W_);
                    a00 = in ? *(const f16x8*)&xbT[((size_t)(yc * W_ + xc)) * 64 + c0] : splat8((_Float16)0.0f);
                }
                if (!(okk & 2)) {
                    const int yc = min(max(y0, 0), H_ - 1), xc = min(max(x0 + 1, 0), W_ - 1);
                    const bool in = ((unsigned)y0 < H_) && ((unsigned)(x0 + 1) < W_);
                    a01 = in ? *(const f16x8*)&xbT[((size_t)(yc * W_ + xc)) * 64 + c0] : splat8((_Float16)0.0f);
                }
                if (!(okk & 4)) {
                    const int yc = min(max(y0 + 1, 0), H_ - 1), xc = min(max(x0, 0), W_ - 1);
                    const bool in = ((unsigned)(y0 + 1) < H_) && ((unsigned)x0 < W_);
                    a10 = in ? *(const f16x8*)&xbT[((size_t)(yc * W_ + xc)) * 64 + c0] : splat8((_Float16)0.0f);
                }
                if (!(okk & 8)) {
                    const int yc = min(max(y0 + 1, 0), H_ - 1), xc = min(max(x0 + 1, 0), W_ - 1);
                    const bool in = ((unsigned)(y0 + 1) < H_) && ((unsigned)(x0 + 1) < W_);
                    a11 = in ? *(const f16x8*)&xbT[((size_t)(yc * W_ + xc)) * 64 + c0] : splat8((_Float16)0.0f);
                }
            }

            f16x8 r = a00 * splat8((_Float16)w00k[k]);
            r = a01 * splat8((_Float16)w01k[k]) + r;
            r = a10 * splat8((_Float16)w10k[k]) + r;
            r = a11 * splat8((_Float16)w11k[k]) + r;

#pragma unroll
            for (int mt = 0; mt < 4; ++mt)
                acc[mt] = __builtin_amdgcn_mfma_f32_16x16x32_f16(af[mt], r, acc[mt], 0, 0, 0);
        }
    }

    // Epilogue B: D col = ln -> px, row = o.
    float* __restrict__ ob = out + (size_t)b * O_ * HW_ + (size_t)ho * W_;
#pragma unroll
    for (int mt = 0; mt < 4; ++mt)
#pragma unroll
        for (int r = 0; r < 4; ++r) {
            const int o = mt * 16 + lq * 4 + r;
            ob[(size_t)o * HW_ + wo] = acc[mt][r];
        }
}

extern "C" void kernel_launch(void* const* d_in, const int* in_sizes, int n_in,
                              void* d_out, int out_size, void* d_ws, size_t ws_size,
                              hipStream_t stream) {
    (void)in_sizes; (void)n_in; (void)out_size; (void)ws_size;
    const float* x    = (const float*)d_in[0];
    const float* offw = (const float*)d_in[1];
    const float* offb = (const float*)d_in[2];
    const float* modw = (const float*)d_in[3];
    const float* modb = (const float*)d_in[4];
    const float* wgt  = (const float*)d_in[5];
    float* out = (float*)d_out;

    _Float16* wpM = (_Float16*)d_ws;                                   // 73728 B
    _Float16* wpA = (_Float16*)((char*)d_ws + WPM_BYTES);              // 36864 B
    _Float16* xT  = (_Float16*)((char*)d_ws + WPM_BYTES + WPA_BYTES);  // 16.78 MB

    prep_kernel<<<TB2_ + 27, 256, 0, stream>>>(x, offw, modw, wgt, xT, wpM, wpA);
    dcn_main_kernel<<<B_ * H_ * 2, 256, 0, stream>>>(xT, wpA, wpM, offb, modb, out);
}

// Round 8
// 147.618 us; speedup vs baseline: 1.0518x; 1.0518x over previous
//
#include <hip/hip_runtime.h>
#include <math.h>

// Problem constants
#define B_   8
#define C_   64
#define O_   64
#define H_   128
#define W_   128
#define HW_  (H_ * W_)
#define KSZ  576            // C_*9 contraction length

typedef _Float16 f16x8 __attribute__((ext_vector_type(8)));
typedef float    f32x4 __attribute__((ext_vector_type(4)));

#define WPM_BYTES (18 * 4 * 64 * 8 * 2)   // 73728
#define WPA_BYTES (18 * 2 * 64 * 8 * 2)   // 36864
#define TB2_      (B_ * HW_ / 128)        // 1024 transpose tiles (128 px x 64 ch)

// ---------------------------------------------------------------------------
// Prep kernel (unchanged — vectorized transpose + weight prepack).
// ---------------------------------------------------------------------------
__global__ __launch_bounds__(256) void prep_kernel(
    const float* __restrict__ x,
    const float* __restrict__ offw, const float* __restrict__ modw,
    const float* __restrict__ wgt,
    _Float16* __restrict__ xT, _Float16* __restrict__ wpM, _Float16* __restrict__ wpA)
{
    const int bi = blockIdx.x;
    if (bi < TB2_) {
        __shared__ _Float16 tile[128 * 68];
        const int tid = threadIdx.x;
        const int b      = bi >> 7;
        const int pxbase = (bi & 127) * 128;

        const int px4   = (tid & 31) * 4;
        const int cbase = tid >> 5;
        const float* __restrict__ xp = x + (size_t)b * C_ * HW_ + pxbase;
#pragma unroll
        for (int r = 0; r < 8; ++r) {
            const int c = cbase + r * 8;
            const f32x4 v = *(const f32x4*)&xp[(size_t)c * HW_ + px4];
#pragma unroll
            for (int i = 0; i < 4; ++i)
                tile[(px4 + i) * 68 + c] = (_Float16)v[i];
        }
        __syncthreads();

        const int px = tid >> 1;
        const int c0 = (tid & 1) * 32;
        f16x8 w[4];
#pragma unroll
        for (int q = 0; q < 4; ++q)
#pragma unroll
            for (int j = 0; j < 8; ++j)
                w[q][j] = tile[px * 68 + c0 + q * 8 + j];
        _Float16* __restrict__ op = xT + ((size_t)b * HW_ + pxbase + px) * 64 + c0;
#pragma unroll
        for (int q = 0; q < 4; ++q)
            *(f16x8*)&op[q * 8] = w[q];
        return;
    }
    const int g = (bi - TB2_) * 256 + threadIdx.x;
    if (g < 18 * 4 * 64) {
        const int s = g >> 8, mt = (g >> 6) & 3, lane = g & 63;
        const int k = s >> 1, cb = (s & 1) * 32;
        const int o  = mt * 16 + (lane & 15);
        const int c0 = cb + (lane >> 4) * 8;
        f16x8 v;
#pragma unroll
        for (int j = 0; j < 8; ++j) v[j] = (_Float16)wgt[o * KSZ + (c0 + j) * 9 + k];
        *(f16x8*)&wpM[(size_t)g * 8] = v;
    } else if (g < 18 * 4 * 64 + 18 * 2 * 64) {
        const int u = g - 18 * 4 * 64;
        const int s = u >> 7, mt = (u >> 6) & 1, lane = u & 63;
        const int k = s >> 1, cb = (s & 1) * 32;
        const int t  = mt * 16 + (lane & 15);
        const int c0 = cb + (lane >> 4) * 8;
        f16x8 v;
#pragma unroll
        for (int j = 0; j < 8; ++j) {
            float w = 0.0f;
            if (t < 18)      w = offw[t * KSZ + (c0 + j) * 9 + k];
            else if (t < 27) w = modw[(t - 18) * KSZ + (c0 + j) * 9 + k];
            v[j] = (_Float16)w;
        }
        *(f16x8*)&wpA[(size_t)u * 8] = v;
    }
}

__device__ __forceinline__ f16x8 splat8(_Float16 h) {
    f16x8 v = {h, h, h, h, h, h, h, h};
    return v;
}

// ---------------------------------------------------------------------------
// Fused main kernel (v7 resubmit — r7 was a broker failure, "container
// failed twice"; the kernel never ran. Resubmitting byte-identical.)
// Ledger: v3 (clamp-staged, inline per-k) = 57.2us BEST; v4 (zero-pad +
// hoisted precompute) = 61.7 (hoist re-sunk, blamed); v6 (zero-pad +
// channel-split restage) = 68.2 (restage blamed). v7 isolates the good
// part: v3's exact loop structure, with
//  (1) ZERO-padded window staging: out-of-image slots hold 0, matching the
//      reference's value-zeroing. Deletes phase-A validity select and
//      phase-B image-bounds tests / clamps / weight-zero selects
//      (~20 VALU per tap). Window slots indexed by RAW coords (zero-pad
//      makes raw lookup correct); in-window clamp only guards the LDS
//      address, with v6's proven UB-free rare fallback (nibble flags).
//  (2) __launch_bounds__(256,2): LDS (62.7KB) caps residency at 2
//      blocks/CU regardless, so a 256-VGPR budget is free scheduling
//      headroom for the unrolled hot loop's load pipelining.
// ---------------------------------------------------------------------------
#define WROWS 7
#define WCOLS 70

#define PP_IDX(t) (((t) & 3) | (((t) >> 4) << 2))
#define PP_SRC(t) ((((t) & 15) >> 2) * 16)

__global__ __launch_bounds__(256, 2) void dcn_main_kernel(
    const _Float16* __restrict__ xT,    // (B, H, W, C) f16
    const _Float16* __restrict__ wpA,   // packed offset/mod weight frags
    const _Float16* __restrict__ wpM,   // packed main weight frags
    const float* __restrict__ offb,     // (18,)
    const float* __restrict__ modb,     // (9,)
    float* __restrict__ out)            // (B, O, H, W)
{
    __shared__ _Float16 win[WROWS * WCOLS * 64];   // 62720 B

    const int tid  = threadIdx.x;
    const int lane = tid & 63;
    const int wave = tid >> 6;
    const int lq   = lane >> 4;
    const int ln   = lane & 15;

    const int bi  = blockIdx.x;
    const int b   = bi & 7;             // XCD-pinned batch
    const int r2  = bi >> 3;            // 0..255
    const int ho  = r2 >> 1;
    const int x0b = (r2 & 1) * 64;
    const int pxw = wave * 16 + ln;     // px within half-row, 0..63
    const int wo  = x0b + pxw;          // this lane's output x

    const _Float16* __restrict__ xbT = xT + (size_t)b * HW_ * 64;

    // ---------------- Stage window (ZERO-padded): rows ho-3..ho+3 ----------
#pragma unroll
    for (int it = 0; it < 16; ++it) {
        const int e = it * 256 + tid;
        if (e < WROWS * WCOLS * 8) {
            const int r   = e / (WCOLS * 8);
            const int rem = e - r * (WCOLS * 8);
            const int cx  = rem >> 3;
            const int q   = rem & 7;
            const int yr  = ho - 3 + r;
            const int xc  = x0b - 3 + cx;
            f16x8 v = splat8((_Float16)0.0f);
            if (((unsigned)yr < H_) && ((unsigned)xc < W_))
                v = *(const f16x8*)&xbT[((size_t)(yr * W_ + xc)) * 64 + q * 8];
            *(f16x8*)&win[(r * WCOLS + cx) * 64 + ((q ^ (cx & 7)) * 8)] = v;
        }
    }
    __syncthreads();

    // ---------------- Phase A: offset/modulator conv via MFMA (no branches)
    f32x4 accA[2];
#pragma unroll
    for (int mt = 0; mt < 2; ++mt) accA[mt] = (f32x4){0.f, 0.f, 0.f, 0.f};

#pragma unroll
    for (int s = 0; s < 18; ++s) {
        const int k = s >> 1, h = s & 1;
        const int ki = k / 3, kj = k - ki * 3;
        f16x8 afA[2];
#pragma unroll
        for (int mt = 0; mt < 2; ++mt)
            afA[mt] = *(const f16x8*)&wpA[(size_t)((s * 2 + mt) * 64 + lane) * 8];
        const int sy = ki + 2;
        const int sx = pxw + kj + 2;
        const int chunk = h * 4 + lq;
        const f16x8 bfA = *(const f16x8*)&win[(sy * WCOLS + sx) * 64 + ((chunk ^ (sx & 7)) * 8)];
#pragma unroll
        for (int mt = 0; mt < 2; ++mt)
            accA[mt] = __builtin_amdgcn_mfma_f32_16x16x32_f16(afA[mt], bfA, accA[mt], 0, 0, 0);
    }

    // Params in registers: lane (lq,ln) owns t = mt*16 + lq*4 + r for px ln.
    float pp[8];
#pragma unroll
    for (int mt = 0; mt < 2; ++mt)
#pragma unroll
        for (int r = 0; r < 4; ++r) {
            const int t = mt * 16 + lq * 4 + r;
            const float val = accA[mt][r];
            float o = 0.0f;
            if (t < 18)      o = val + offb[t];
            else if (t < 27) o = 2.0f / (1.0f + expf(-(val + modb[t - 18])));
            pp[mt * 4 + r] = o;
        }

    // ---------------- Phase B: deformable gather (LDS) + MFMA --------------
    f32x4 acc[4];
#pragma unroll
    for (int mt = 0; mt < 4; ++mt) acc[mt] = (f32x4){0.f, 0.f, 0.f, 0.f};

#pragma unroll
    for (int k = 0; k < 9; ++k) {
        const int ki = k / 3, kj = k - ki * 3;

        // broadcast this px's params from owner lanes (intra-wave)
        const float dy = __shfl(pp[PP_IDX(2 * k)],     PP_SRC(2 * k) + ln, 64);
        const float dx = __shfl(pp[PP_IDX(2 * k + 1)], PP_SRC(2 * k + 1) + ln, 64);
        const float mk = __shfl(pp[PP_IDX(18 + k)],    PP_SRC(18 + k) + ln, 64);

        const float ys = (float)(ho - 1 + ki) + dy;
        const float xs = (float)(wo - 1 + kj) + dx;
        const float y0f = floorf(ys), x0f = floorf(xs);
        const float wy = ys - y0f, wx = xs - x0f;
        const int y0 = (int)y0f, x0 = (int)x0f;
        const float wyc = 1.0f - wy, wxc = 1.0f - wx;
        const float w00 = wyc * wxc * mk;
        const float w01 = wyc * wx  * mk;
        const float w10 = wy  * wxc * mk;
        const float w11 = wy  * wx  * mk;

        // window slots from RAW coords (zero-pad makes raw lookup correct)
        const int sy0 = y0 - ho + 3, sy1 = sy0 + 1;
        const int sx0 = x0 - x0b + 3, sx1 = sx0 + 1;
        const int ok00 = ((unsigned)sy0 < WROWS) & ((unsigned)sx0 < WCOLS);
        const int ok01 = ((unsigned)sy0 < WROWS) & ((unsigned)sx1 < WCOLS);
        const int ok10 = ((unsigned)sy1 < WROWS) & ((unsigned)sx0 < WCOLS);
        const int ok11 = ((unsigned)sy1 < WROWS) & ((unsigned)sx1 < WCOLS);
        const int okk  = ok00 | (ok01 << 1) | (ok10 << 2) | (ok11 << 3);
        // safe (in-window) slots for the LDS address; fallback overrides
        const int cy0 = min(max(sy0, 0), WROWS - 1), cy1 = min(max(sy1, 0), WROWS - 1);
        const int cx0 = min(max(sx0, 0), WCOLS - 1), cx1 = min(max(sx1, 0), WCOLS - 1);
        const int b00 = (cy0 * WCOLS + cx0) * 64, x7_00 = cx0 & 7;
        const int b01 = (cy0 * WCOLS + cx1) * 64, x7_01 = cx1 & 7;
        const int b10 = (cy1 * WCOLS + cx0) * 64, x7_10 = cx0 & 7;
        const int b11 = (cy1 * WCOLS + cx1) * 64, x7_11 = cx1 & 7;

        const f16x8 w00v = splat8((_Float16)w00);
        const f16x8 w01v = splat8((_Float16)w01);
        const f16x8 w10v = splat8((_Float16)w10);
        const f16x8 w11v = splat8((_Float16)w11);

#pragma unroll
        for (int h = 0; h < 2; ++h) {
            const int s = 2 * k + h;
            const int chunk = h * 4 + lq;
            const int c0 = h * 32 + lq * 8;

            f16x8 af[4];
#pragma unroll
            for (int mt = 0; mt < 4; ++mt)
                af[mt] = *(const f16x8*)&wpM[(size_t)((s * 4 + mt) * 64 + lane) * 8];

            f16x8 a00 = *(const f16x8*)&win[b00 + ((chunk ^ x7_00) * 8)];
            f16x8 a01 = *(const f16x8*)&win[b01 + ((chunk ^ x7_01) * 8)];
            f16x8 a10 = *(const f16x8*)&win[b10 + ((chunk ^ x7_10) * 8)];
            f16x8 a11 = *(const f16x8*)&win[b11 + ((chunk ^ x7_11) * 8)];

            // rare fallback: corner outside window (value zeroed if off-image)
            if (__builtin_expect(okk != 15, 0)) {
                if (!ok00) {
                    const int yc = min(max(y0, 0), H_ - 1), xc = min(max(x0, 0), W_ - 1);
                    const bool in = ((unsigned)y0 < H_) && ((unsigned)x0 < W_);
                    a00 = in ? *(const f16x8*)&xbT[((size_t)(yc * W_ + xc)) * 64 + c0] : splat8((_Float16)0.0f);
                }
                if (!ok01) {
                    const int yc = min(max(y0, 0), H_ - 1), xc = min(max(x0 + 1, 0), W_ - 1);
                    const bool in = ((unsigned)y0 < H_) && ((unsigned)(x0 + 1) < W_);
                    a01 = in ? *(const f16x8*)&xbT[((size_t)(yc * W_ + xc)) * 64 + c0] : splat8((_Float16)0.0f);
                }
                if (!ok10) {
                    const int yc = min(max(y0 + 1, 0), H_ - 1), xc = min(max(x0, 0), W_ - 1);
                    const bool in = ((unsigned)(y0 + 1) < H_) && ((unsigned)x0 < W_);
                    a10 = in ? *(const f16x8*)&xbT[((size_t)(yc * W_ + xc)) * 64 + c0] : splat8((_Float16)0.0f);
                }
                if (!ok11) {
                    const int yc = min(max(y0 + 1, 0), H_ - 1), xc = min(max(x0 + 1, 0), W_ - 1);
                    const bool in = ((unsigned)(y0 + 1) < H_) && ((unsigned)(x0 + 1) < W_);
                    a11 = in ? *(const f16x8*)&xbT[((size_t)(yc * W_ + xc)) * 64 + c0] : splat8((_Float16)0.0f);
                }
            }

            f16x8 r = a00 * w00v;
            r = a01 * w01v + r;
            r = a10 * w10v + r;
            r = a11 * w11v + r;

#pragma unroll
            for (int mt = 0; mt < 4; ++mt)
                acc[mt] = __builtin_amdgcn_mfma_f32_16x16x32_f16(af[mt], r, acc[mt], 0, 0, 0);
        }
    }

    // Epilogue B: D col = ln -> px, row = o.
    float* __restrict__ ob = out + (size_t)b * O_ * HW_ + (size_t)ho * W_;
#pragma unroll
    for (int mt = 0; mt < 4; ++mt)
#pragma unroll
        for (int r = 0; r < 4; ++r) {
            const int o = mt * 16 + lq * 4 + r;
            ob[(size_t)o * HW_ + wo] = acc[mt][r];
        }
}

extern "C" void kernel_launch(void* const* d_in, const int* in_sizes, int n_in,
                              void* d_out, int out_size, void* d_ws, size_t ws_size,
                              hipStream_t stream) {
    (void)in_sizes; (void)n_in; (void)out_size; (void)ws_size;
    const float* x    = (const float*)d_in[0];
    const float* offw = (const float*)d_in[1];
    const float* offb = (const float*)d_in[2];
    const float* modw = (const float*)d_in[3];
    const float* modb = (const float*)d_in[4];
    const float* wgt  = (const float*)d_in[5];
    float* out = (float*)d_out;

    _Float16* wpM = (_Float16*)d_ws;                                   // 73728 B
    _Float16* wpA = (_Float16*)((char*)d_ws + WPM_BYTES);              // 36864 B
    _Float16* xT  = (_Float16*)((char*)d_ws + WPM_BYTES + WPA_BYTES);  // 16.78 MB

    prep_kernel<<<TB2_ + 27, 256, 0, stream>>>(x, offw, modw, wgt, xT, wpM, wpA);
    dcn_main_kernel<<<B_ * H_ * 2, 256, 0, stream>>>(xT, wpA, wpM, offb, modb, out);
}

// Round 9
// 137.650 us; speedup vs baseline: 1.1280x; 1.0724x over previous
//
#include <hip/hip_runtime.h>
#include <math.h>

// Problem constants
#define B_   8
#define C_   64
#define O_   64
#define H_   128
#define W_   128
#define HW_  (H_ * W_)
#define KSZ  576            // C_*9 contraction length

typedef _Float16 f16x8 __attribute__((ext_vector_type(8)));
typedef float    f32x4 __attribute__((ext_vector_type(4)));

#define WPM_BYTES (18 * 4 * 64 * 8 * 2)   // 73728
#define WPA_BYTES (18 * 2 * 64 * 8 * 2)   // 36864
#define TB2_      (B_ * HW_ / 128)        // 1024 transpose tiles (128 px x 64 ch)

// ---------------------------------------------------------------------------
// Prep kernel (unchanged — vectorized transpose + weight prepack).
// ---------------------------------------------------------------------------
__global__ __launch_bounds__(256) void prep_kernel(
    const float* __restrict__ x,
    const float* __restrict__ offw, const float* __restrict__ modw,
    const float* __restrict__ wgt,
    _Float16* __restrict__ xT, _Float16* __restrict__ wpM, _Float16* __restrict__ wpA)
{
    const int bi = blockIdx.x;
    if (bi < TB2_) {
        __shared__ _Float16 tile[128 * 68];
        const int tid = threadIdx.x;
        const int b      = bi >> 7;
        const int pxbase = (bi & 127) * 128;

        const int px4   = (tid & 31) * 4;
        const int cbase = tid >> 5;
        const float* __restrict__ xp = x + (size_t)b * C_ * HW_ + pxbase;
#pragma unroll
        for (int r = 0; r < 8; ++r) {
            const int c = cbase + r * 8;
            const f32x4 v = *(const f32x4*)&xp[(size_t)c * HW_ + px4];
#pragma unroll
            for (int i = 0; i < 4; ++i)
                tile[(px4 + i) * 68 + c] = (_Float16)v[i];
        }
        __syncthreads();

        const int px = tid >> 1;
        const int c0 = (tid & 1) * 32;
        f16x8 w[4];
#pragma unroll
        for (int q = 0; q < 4; ++q)
#pragma unroll
            for (int j = 0; j < 8; ++j)
                w[q][j] = tile[px * 68 + c0 + q * 8 + j];
        _Float16* __restrict__ op = xT + ((size_t)b * HW_ + pxbase + px) * 64 + c0;
#pragma unroll
        for (int q = 0; q < 4; ++q)
            *(f16x8*)&op[q * 8] = w[q];
        return;
    }
    const int g = (bi - TB2_) * 256 + threadIdx.x;
    if (g < 18 * 4 * 64) {
        const int s = g >> 8, mt = (g >> 6) & 3, lane = g & 63;
        const int k = s >> 1, cb = (s & 1) * 32;
        const int o  = mt * 16 + (lane & 15);
        const int c0 = cb + (lane >> 4) * 8;
        f16x8 v;
#pragma unroll
        for (int j = 0; j < 8; ++j) v[j] = (_Float16)wgt[o * KSZ + (c0 + j) * 9 + k];
        *(f16x8*)&wpM[(size_t)g * 8] = v;
    } else if (g < 18 * 4 * 64 + 18 * 2 * 64) {
        const int u = g - 18 * 4 * 64;
        const int s = u >> 7, mt = (u >> 6) & 1, lane = u & 63;
        const int k = s >> 1, cb = (s & 1) * 32;
        const int t  = mt * 16 + (lane & 15);
        const int c0 = cb + (lane >> 4) * 8;
        f16x8 v;
#pragma unroll
        for (int j = 0; j < 8; ++j) {
            float w = 0.0f;
            if (t < 18)      w = offw[t * KSZ + (c0 + j) * 9 + k];
            else if (t < 27) w = modw[(t - 18) * KSZ + (c0 + j) * 9 + k];
            v[j] = (_Float16)w;
        }
        *(f16x8*)&wpA[(size_t)u * 8] = v;
    }
}

__device__ __forceinline__ f16x8 splat8(_Float16 h) {
    f16x8 v = {h, h, h, h, h, h, h, h};
    return v;
}

// ---------------------------------------------------------------------------
// Fused main kernel (v8 — 2x32-px block shape; only delta vs v7).
// Ledger: v3=57.2, v4=61.7, v6=68.2, v7=60.0 (zero-pad neutral-to-noise;
// VALU trims don't move this kernel). v8 attacks staging volume AND
// occupancy with zero added work by reshaping the block:
//   1x64 px, 7x70 window (490 cells, 62.7KB, 2 blocks/CU)
//   -> 2x32 px, 8x38 window (304 cells/64px = -38% staging, 38.9KB LDS,
//      4 blocks/CU = 16 waves/CU).
// Same grid (2048), same per-px compute, same +-3 wings both axes
// (sy0 in [0,7], sx0 in [0,37] for |d|<2 — verified), no restage/barriers.
// Wave w: wrow=w>>1 (output row ho+wrow), wcol=w&1 (px 16-col half).
// ---------------------------------------------------------------------------
#define WROWS 8
#define WCOLS 38

#define PP_IDX(t) (((t) & 3) | (((t) >> 4) << 2))
#define PP_SRC(t) ((((t) & 15) >> 2) * 16)

__global__ __launch_bounds__(256) void dcn_main_kernel(
    const _Float16* __restrict__ xT,    // (B, H, W, C) f16
    const _Float16* __restrict__ wpA,   // packed offset/mod weight frags
    const _Float16* __restrict__ wpM,   // packed main weight frags
    const float* __restrict__ offb,     // (18,)
    const float* __restrict__ modb,     // (9,)
    float* __restrict__ out)            // (B, O, H, W)
{
    __shared__ _Float16 win[WROWS * WCOLS * 64];   // 38912 B

    const int tid  = threadIdx.x;
    const int lane = tid & 63;
    const int wave = tid >> 6;
    const int lq   = lane >> 4;
    const int ln   = lane & 15;

    const int bi   = blockIdx.x;
    const int b    = bi & 7;            // XCD-pinned batch
    const int rest = bi >> 3;           // 0..255
    const int ho   = (rest >> 2) * 2;   // row-pair base
    const int x0b  = (rest & 3) * 32;   // col-quarter base

    const int wrow = wave >> 1;         // 0/1: output row ho+wrow
    const int wcol = wave & 1;          // 0/1: px 16-col half
    const int yo   = ho + wrow;         // this wave's output row
    const int pxw  = wcol * 16 + ln;    // px within 32-col tile, 0..31
    const int wo   = x0b + pxw;         // this lane's output x

    const _Float16* __restrict__ xbT = xT + (size_t)b * HW_ * 64;

    // ---------------- Stage window (ZERO-padded): rows ho-3..ho+4, ---------
    // cols x0b-3..x0b+34.  8*38*8 = 2432 chunk-slots.
#pragma unroll
    for (int it = 0; it < 10; ++it) {
        const int e = it * 256 + tid;
        if (e < WROWS * WCOLS * 8) {
            const int r   = e / (WCOLS * 8);
            const int rem = e - r * (WCOLS * 8);
            const int cx  = rem >> 3;
            const int q   = rem & 7;
            const int yr  = ho - 3 + r;
            const int xc  = x0b - 3 + cx;
            f16x8 v = splat8((_Float16)0.0f);
            if (((unsigned)yr < H_) && ((unsigned)xc < W_))
                v = *(const f16x8*)&xbT[((size_t)(yr * W_ + xc)) * 64 + q * 8];
            *(f16x8*)&win[(r * WCOLS + cx) * 64 + ((q ^ (cx & 7)) * 8)] = v;
        }
    }
    __syncthreads();

    // ---------------- Phase A: offset/modulator conv via MFMA (no branches)
    f32x4 accA[2];
#pragma unroll
    for (int mt = 0; mt < 2; ++mt) accA[mt] = (f32x4){0.f, 0.f, 0.f, 0.f};

#pragma unroll
    for (int s = 0; s < 18; ++s) {
        const int k = s >> 1, h = s & 1;
        const int ki = k / 3, kj = k - ki * 3;
        f16x8 afA[2];
#pragma unroll
        for (int mt = 0; mt < 2; ++mt)
            afA[mt] = *(const f16x8*)&wpA[(size_t)((s * 2 + mt) * 64 + lane) * 8];
        const int sy = wrow + ki + 2;        // row (yo-1+ki) rel to ho-3
        const int sx = pxw + kj + 2;         // col (wo-1+kj) rel to x0b-3
        const int chunk = h * 4 + lq;
        const f16x8 bfA = *(const f16x8*)&win[(sy * WCOLS + sx) * 64 + ((chunk ^ (sx & 7)) * 8)];
#pragma unroll
        for (int mt = 0; mt < 2; ++mt)
            accA[mt] = __builtin_amdgcn_mfma_f32_16x16x32_f16(afA[mt], bfA, accA[mt], 0, 0, 0);
    }

    // Params in registers: lane (lq,ln) owns t = mt*16 + lq*4 + r for px ln.
    float pp[8];
#pragma unroll
    for (int mt = 0; mt < 2; ++mt)
#pragma unroll
        for (int r = 0; r < 4; ++r) {
            const int t = mt * 16 + lq * 4 + r;
            const float val = accA[mt][r];
            float o = 0.0f;
            if (t < 18)      o = val + offb[t];
            else if (t < 27) o = 2.0f / (1.0f + expf(-(val + modb[t - 18])));
            pp[mt * 4 + r] = o;
        }

    // ---------------- Phase B: deformable gather (LDS) + MFMA --------------
    f32x4 acc[4];
#pragma unroll
    for (int mt = 0; mt < 4; ++mt) acc[mt] = (f32x4){0.f, 0.f, 0.f, 0.f};

#pragma unroll
    for (int k = 0; k < 9; ++k) {
        const int ki = k / 3, kj = k - ki * 3;

        // broadcast this px's params from owner lanes (intra-wave)
        const float dy = __shfl(pp[PP_IDX(2 * k)],     PP_SRC(2 * k) + ln, 64);
        const float dx = __shfl(pp[PP_IDX(2 * k + 1)], PP_SRC(2 * k + 1) + ln, 64);
        const float mk = __shfl(pp[PP_IDX(18 + k)],    PP_SRC(18 + k) + ln, 64);

        const float ys = (float)(yo - 1 + ki) + dy;
        const float xs = (float)(wo - 1 + kj) + dx;
        const float y0f = floorf(ys), x0f = floorf(xs);
        const float wy = ys - y0f, wx = xs - x0f;
        const int y0 = (int)y0f, x0 = (int)x0f;
        const float wyc = 1.0f - wy, wxc = 1.0f - wx;
        const float w00 = wyc * wxc * mk;
        const float w01 = wyc * wx  * mk;
        const float w10 = wy  * wxc * mk;
        const float w11 = wy  * wx  * mk;

        // window slots from RAW coords (zero-pad makes raw lookup correct)
        const int sy0 = y0 - ho + 3, sy1 = sy0 + 1;
        const int sx0 = x0 - x0b + 3, sx1 = sx0 + 1;
        const int ok00 = ((unsigned)sy0 < WROWS) & ((unsigned)sx0 < WCOLS);
        const int ok01 = ((unsigned)sy0 < WROWS) & ((unsigned)sx1 < WCOLS);
        const int ok10 = ((unsigned)sy1 < WROWS) & ((unsigned)sx0 < WCOLS);
        const int ok11 = ((unsigned)sy1 < WROWS) & ((unsigned)sx1 < WCOLS);
        const int okk  = ok00 | (ok01 << 1) | (ok10 << 2) | (ok11 << 3);
        // safe (in-window) slots for the LDS address; fallback overrides
        const int cy0 = min(max(sy0, 0), WROWS - 1), cy1 = min(max(sy1, 0), WROWS - 1);
        const int cx0 = min(max(sx0, 0), WCOLS - 1), cx1 = min(max(sx1, 0), WCOLS - 1);
        const int b00 = (cy0 * WCOLS + cx0) * 64, x7_00 = cx0 & 7;
        const int b01 = (cy0 * WCOLS + cx1) * 64, x7_01 = cx1 & 7;
        const int b10 = (cy1 * WCOLS + cx0) * 64, x7_10 = cx0 & 7;
        const int b11 = (cy1 * WCOLS + cx1) * 64, x7_11 = cx1 & 7;

        const f16x8 w00v = splat8((_Float16)w00);
        const f16x8 w01v = splat8((_Float16)w01);
        const f16x8 w10v = splat8((_Float16)w10);
        const f16x8 w11v = splat8((_Float16)w11);

#pragma unroll
        for (int h = 0; h < 2; ++h) {
            const int s = 2 * k + h;
            const int chunk = h * 4 + lq;
            const int c0 = h * 32 + lq * 8;

            f16x8 af[4];
#pragma unroll
            for (int mt = 0; mt < 4; ++mt)
                af[mt] = *(const f16x8*)&wpM[(size_t)((s * 4 + mt) * 64 + lane) * 8];

            f16x8 a00 = *(const f16x8*)&win[b00 + ((chunk ^ x7_00) * 8)];
            f16x8 a01 = *(const f16x8*)&win[b01 + ((chunk ^ x7_01) * 8)];
            f16x8 a10 = *(const f16x8*)&win[b10 + ((chunk ^ x7_10) * 8)];
            f16x8 a11 = *(const f16x8*)&win[b11 + ((chunk ^ x7_11) * 8)];

            // rare fallback: corner outside window (value zeroed if off-image)
            if (__builtin_expect(okk != 15, 0)) {
                if (!ok00) {
                    const int yc = min(max(y0, 0), H_ - 1), xc = min(max(x0, 0), W_ - 1);
                    const bool in = ((unsigned)y0 < H_) && ((unsigned)x0 < W_);
                    a00 = in ? *(const f16x8*)&xbT[((size_t)(yc * W_ + xc)) * 64 + c0] : splat8((_Float16)0.0f);
                }
                if (!ok01) {
                    const int yc = min(max(y0, 0), H_ - 1), xc = min(max(x0 + 1, 0), W_ - 1);
                    const bool in = ((unsigned)y0 < H_) && ((unsigned)(x0 + 1) < W_);
                    a01 = in ? *(const f16x8*)&xbT[((size_t)(yc * W_ + xc)) * 64 + c0] : splat8((_Float16)0.0f);
                }
                if (!ok10) {
                    const int yc = min(max(y0 + 1, 0), H_ - 1), xc = min(max(x0, 0), W_ - 1);
                    const bool in = ((unsigned)(y0 + 1) < H_) && ((unsigned)x0 < W_);
                    a10 = in ? *(const f16x8*)&xbT[((size_t)(yc * W_ + xc)) * 64 + c0] : splat8((_Float16)0.0f);
                }
                if (!ok11) {
                    const int yc = min(max(y0 + 1, 0), H_ - 1), xc = min(max(x0 + 1, 0), W_ - 1);
                    const bool in = ((unsigned)(y0 + 1) < H_) && ((unsigned)(x0 + 1) < W_);
                    a11 = in ? *(const f16x8*)&xbT[((size_t)(yc * W_ + xc)) * 64 + c0] : splat8((_Float16)0.0f);
                }
            }

            f16x8 r = a00 * w00v;
            r = a01 * w01v + r;
            r = a10 * w10v + r;
            r = a11 * w11v + r;

#pragma unroll
            for (int mt = 0; mt < 4; ++mt)
                acc[mt] = __builtin_amdgcn_mfma_f32_16x16x32_f16(af[mt], r, acc[mt], 0, 0, 0);
        }
    }

    // Epilogue B: D col = ln -> px, row = o.
    float* __restrict__ ob = out + (size_t)b * O_ * HW_ + (size_t)yo * W_;
#pragma unroll
    for (int mt = 0; mt < 4; ++mt)
#pragma unroll
        for (int r = 0; r < 4; ++r) {
            const int o = mt * 16 + lq * 4 + r;
            ob[(size_t)o * HW_ + wo] = acc[mt][r];
        }
}

extern "C" void kernel_launch(void* const* d_in, const int* in_sizes, int n_in,
                              void* d_out, int out_size, void* d_ws, size_t ws_size,
                              hipStream_t stream) {
    (void)in_sizes; (void)n_in; (void)out_size; (void)ws_size;
    const float* x    = (const float*)d_in[0];
    const float* offw = (const float*)d_in[1];
    const float* offb = (const float*)d_in[2];
    const float* modw = (const float*)d_in[3];
    const float* modb = (const float*)d_in[4];
    const float* wgt  = (const float*)d_in[5];
    float* out = (float*)d_out;

    _Float16* wpM = (_Float16*)d_ws;                                   // 73728 B
    _Float16* wpA = (_Float16*)((char*)d_ws + WPM_BYTES);              // 36864 B
    _Float16* xT  = (_Float16*)((char*)d_ws + WPM_BYTES + WPA_BYTES);  // 16.78 MB

    prep_kernel<<<TB2_ + 27, 256, 0, stream>>>(x, offw, modw, wgt, xT, wpM, wpA);
    dcn_main_kernel<<<B_ * H_ * 2, 256, 0, stream>>>(xT, wpA, wpM, offb, modb, out);
}

// Round 10
// 134.866 us; speedup vs baseline: 1.1513x; 1.0206x over previous
//
#include <hip/hip_runtime.h>
#include <math.h>

// Problem constants
#define B_   8
#define C_   64
#define O_   64
#define H_   128
#define W_   128
#define HW_  (H_ * W_)
#define KSZ  576            // C_*9 contraction length

typedef _Float16 f16x8 __attribute__((ext_vector_type(8)));
typedef float    f32x4 __attribute__((ext_vector_type(4)));

#define WPM_BYTES (18 * 4 * 64 * 8 * 2)   // 73728
#define WPA_BYTES (18 * 2 * 64 * 8 * 2)   // 36864
#define TB2_      (B_ * HW_ / 128)        // 1024 transpose tiles (128 px x 64 ch)

// ---------------------------------------------------------------------------
// Prep kernel (unchanged — vectorized transpose + weight prepack).
// ---------------------------------------------------------------------------
__global__ __launch_bounds__(256) void prep_kernel(
    const float* __restrict__ x,
    const float* __restrict__ offw, const float* __restrict__ modw,
    const float* __restrict__ wgt,
    _Float16* __restrict__ xT, _Float16* __restrict__ wpM, _Float16* __restrict__ wpA)
{
    const int bi = blockIdx.x;
    if (bi < TB2_) {
        __shared__ _Float16 tile[128 * 68];
        const int tid = threadIdx.x;
        const int b      = bi >> 7;
        const int pxbase = (bi & 127) * 128;

        const int px4   = (tid & 31) * 4;
        const int cbase = tid >> 5;
        const float* __restrict__ xp = x + (size_t)b * C_ * HW_ + pxbase;
#pragma unroll
        for (int r = 0; r < 8; ++r) {
            const int c = cbase + r * 8;
            const f32x4 v = *(const f32x4*)&xp[(size_t)c * HW_ + px4];
#pragma unroll
            for (int i = 0; i < 4; ++i)
                tile[(px4 + i) * 68 + c] = (_Float16)v[i];
        }
        __syncthreads();

        const int px = tid >> 1;
        const int c0 = (tid & 1) * 32;
        f16x8 w[4];
#pragma unroll
        for (int q = 0; q < 4; ++q)
#pragma unroll
            for (int j = 0; j < 8; ++j)
                w[q][j] = tile[px * 68 + c0 + q * 8 + j];
        _Float16* __restrict__ op = xT + ((size_t)b * HW_ + pxbase + px) * 64 + c0;
#pragma unroll
        for (int q = 0; q < 4; ++q)
            *(f16x8*)&op[q * 8] = w[q];
        return;
    }
    const int g = (bi - TB2_) * 256 + threadIdx.x;
    if (g < 18 * 4 * 64) {
        const int s = g >> 8, mt = (g >> 6) & 3, lane = g & 63;
        const int k = s >> 1, cb = (s & 1) * 32;
        const int o  = mt * 16 + (lane & 15);
        const int c0 = cb + (lane >> 4) * 8;
        f16x8 v;
#pragma unroll
        for (int j = 0; j < 8; ++j) v[j] = (_Float16)wgt[o * KSZ + (c0 + j) * 9 + k];
        *(f16x8*)&wpM[(size_t)g * 8] = v;
    } else if (g < 18 * 4 * 64 + 18 * 2 * 64) {
        const int u = g - 18 * 4 * 64;
        const int s = u >> 7, mt = (u >> 6) & 1, lane = u & 63;
        const int k = s >> 1, cb = (s & 1) * 32;
        const int t  = mt * 16 + (lane & 15);
        const int c0 = cb + (lane >> 4) * 8;
        f16x8 v;
#pragma unroll
        for (int j = 0; j < 8; ++j) {
            float w = 0.0f;
            if (t < 18)      w = offw[t * KSZ + (c0 + j) * 9 + k];
            else if (t < 27) w = modw[(t - 18) * KSZ + (c0 + j) * 9 + k];
            v[j] = (_Float16)w;
        }
        *(f16x8*)&wpA[(size_t)u * 8] = v;
    }
}

__device__ __forceinline__ f16x8 splat8(_Float16 h) {
    f16x8 v = {h, h, h, h, h, h, h, h};
    return v;
}

// ---------------------------------------------------------------------------
// Fused main kernel (v9 — 4x16-px block; only delta vs v8).
// Ledger: v3=57.2, v7=60.0, v8=48.8 (2x32 tile: -38% staging, 4 blk/CU).
// v9 continues the proven lever: 4 output rows x 16 cols per block.
//   window 8x38 (304 cells/64px, 38.9KB) -> 11x22 (242 cells/64px = -20%,
//   31.0KB -> 5 blocks/CU = 20 waves/CU).
// Rows ho-3..ho+7: the +7 wing fully covers dy in (-2,2) for the bottom
// row's taps (v8's 8-row window relied on the fallback for dy in [1,2) at
// its bottom tap), so fallback-branch frequency DROPS vs v8.
// Wave = one output row (wrow=wave), 16 px (ln). Same grid 2048.
// ---------------------------------------------------------------------------
#define WROWS 11
#define WCOLS 22

#define PP_IDX(t) (((t) & 3) | (((t) >> 4) << 2))
#define PP_SRC(t) ((((t) & 15) >> 2) * 16)

__global__ __launch_bounds__(256) void dcn_main_kernel(
    const _Float16* __restrict__ xT,    // (B, H, W, C) f16
    const _Float16* __restrict__ wpA,   // packed offset/mod weight frags
    const _Float16* __restrict__ wpM,   // packed main weight frags
    const float* __restrict__ offb,     // (18,)
    const float* __restrict__ modb,     // (9,)
    float* __restrict__ out)            // (B, O, H, W)
{
    __shared__ _Float16 win[WROWS * WCOLS * 64];   // 30976 B

    const int tid  = threadIdx.x;
    const int lane = tid & 63;
    const int wave = tid >> 6;
    const int lq   = lane >> 4;
    const int ln   = lane & 15;

    const int bi   = blockIdx.x;
    const int b    = bi & 7;            // XCD-pinned batch
    const int rest = bi >> 3;           // 0..255
    const int ho   = (rest >> 3) * 4;   // row-quad base (32 groups)
    const int x0b  = (rest & 7) * 16;   // col-sixteenth base (8 groups)

    const int wrow = wave;              // 0..3: output row ho+wrow
    const int yo   = ho + wrow;         // this wave's output row
    const int pxw  = ln;                // px within 16-col tile
    const int wo   = x0b + pxw;         // this lane's output x

    const _Float16* __restrict__ xbT = xT + (size_t)b * HW_ * 64;

    // ---------------- Stage window (ZERO-padded): rows ho-3..ho+7, ---------
    // cols x0b-3..x0b+18.  11*22*8 = 1936 chunk-slots.
#pragma unroll
    for (int it = 0; it < 8; ++it) {
        const int e = it * 256 + tid;
        if (e < WROWS * WCOLS * 8) {
            const int r   = e / (WCOLS * 8);
            const int rem = e - r * (WCOLS * 8);
            const int cx  = rem >> 3;
            const int q   = rem & 7;
            const int yr  = ho - 3 + r;
            const int xc  = x0b - 3 + cx;
            f16x8 v = splat8((_Float16)0.0f);
            if (((unsigned)yr < H_) && ((unsigned)xc < W_))
                v = *(const f16x8*)&xbT[((size_t)(yr * W_ + xc)) * 64 + q * 8];
            *(f16x8*)&win[(r * WCOLS + cx) * 64 + ((q ^ (cx & 7)) * 8)] = v;
        }
    }
    __syncthreads();

    // ---------------- Phase A: offset/modulator conv via MFMA (no branches)
    f32x4 accA[2];
#pragma unroll
    for (int mt = 0; mt < 2; ++mt) accA[mt] = (f32x4){0.f, 0.f, 0.f, 0.f};

#pragma unroll
    for (int s = 0; s < 18; ++s) {
        const int k = s >> 1, h = s & 1;
        const int ki = k / 3, kj = k - ki * 3;
        f16x8 afA[2];
#pragma unroll
        for (int mt = 0; mt < 2; ++mt)
            afA[mt] = *(const f16x8*)&wpA[(size_t)((s * 2 + mt) * 64 + lane) * 8];
        const int sy = wrow + ki + 2;        // row (yo-1+ki) rel to ho-3
        const int sx = pxw + kj + 2;         // col (wo-1+kj) rel to x0b-3
        const int chunk = h * 4 + lq;
        const f16x8 bfA = *(const f16x8*)&win[(sy * WCOLS + sx) * 64 + ((chunk ^ (sx & 7)) * 8)];
#pragma unroll
        for (int mt = 0; mt < 2; ++mt)
            accA[mt] = __builtin_amdgcn_mfma_f32_16x16x32_f16(afA[mt], bfA, accA[mt], 0, 0, 0);
    }

    // Params in registers: lane (lq,ln) owns t = mt*16 + lq*4 + r for px ln.
    float pp[8];
#pragma unroll
    for (int mt = 0; mt < 2; ++mt)
#pragma unroll
        for (int r = 0; r < 4; ++r) {
            const int t = mt * 16 + lq * 4 + r;
            const float val = accA[mt][r];
            float o = 0.0f;
            if (t < 18)      o = val + offb[t];
            else if (t < 27) o = 2.0f / (1.0f + expf(-(val + modb[t - 18])));
            pp[mt * 4 + r] = o;
        }

    // ---------------- Phase B: deformable gather (LDS) + MFMA --------------
    f32x4 acc[4];
#pragma unroll
    for (int mt = 0; mt < 4; ++mt) acc[mt] = (f32x4){0.f, 0.f, 0.f, 0.f};

#pragma unroll
    for (int k = 0; k < 9; ++k) {
        const int ki = k / 3, kj = k - ki * 3;

        // broadcast this px's params from owner lanes (intra-wave)
        const float dy = __shfl(pp[PP_IDX(2 * k)],     PP_SRC(2 * k) + ln, 64);
        const float dx = __shfl(pp[PP_IDX(2 * k + 1)], PP_SRC(2 * k + 1) + ln, 64);
        const float mk = __shfl(pp[PP_IDX(18 + k)],    PP_SRC(18 + k) + ln, 64);

        const float ys = (float)(yo - 1 + ki) + dy;
        const float xs = (float)(wo - 1 + kj) + dx;
        const float y0f = floorf(ys), x0f = floorf(xs);
        const float wy = ys - y0f, wx = xs - x0f;
        const int y0 = (int)y0f, x0 = (int)x0f;
        const float wyc = 1.0f - wy, wxc = 1.0f - wx;
        const float w00 = wyc * wxc * mk;
        const float w01 = wyc * wx  * mk;
        const float w10 = wy  * wxc * mk;
        const float w11 = wy  * wx  * mk;

        // window slots from RAW coords (zero-pad makes raw lookup correct)
        const int sy0 = y0 - ho + 3, sy1 = sy0 + 1;
        const int sx0 = x0 - x0b + 3, sx1 = sx0 + 1;
        const int ok00 = ((unsigned)sy0 < WROWS) & ((unsigned)sx0 < WCOLS);
        const int ok01 = ((unsigned)sy0 < WROWS) & ((unsigned)sx1 < WCOLS);
        const int ok10 = ((unsigned)sy1 < WROWS) & ((unsigned)sx0 < WCOLS);
        const int ok11 = ((unsigned)sy1 < WROWS) & ((unsigned)sx1 < WCOLS);
        const int okk  = ok00 | (ok01 << 1) | (ok10 << 2) | (ok11 << 3);
        // safe (in-window) slots for the LDS address; fallback overrides
        const int cy0 = min(max(sy0, 0), WROWS - 1), cy1 = min(max(sy1, 0), WROWS - 1);
        const int cx0 = min(max(sx0, 0), WCOLS - 1), cx1 = min(max(sx1, 0), WCOLS - 1);
        const int b00 = (cy0 * WCOLS + cx0) * 64, x7_00 = cx0 & 7;
        const int b01 = (cy0 * WCOLS + cx1) * 64, x7_01 = cx1 & 7;
        const int b10 = (cy1 * WCOLS + cx0) * 64, x7_10 = cx0 & 7;
        const int b11 = (cy1 * WCOLS + cx1) * 64, x7_11 = cx1 & 7;

        const f16x8 w00v = splat8((_Float16)w00);
        const f16x8 w01v = splat8((_Float16)w01);
        const f16x8 w10v = splat8((_Float16)w10);
        const f16x8 w11v = splat8((_Float16)w11);

#pragma unroll
        for (int h = 0; h < 2; ++h) {
            const int s = 2 * k + h;
            const int chunk = h * 4 + lq;
            const int c0 = h * 32 + lq * 8;

            f16x8 af[4];
#pragma unroll
            for (int mt = 0; mt < 4; ++mt)
                af[mt] = *(const f16x8*)&wpM[(size_t)((s * 4 + mt) * 64 + lane) * 8];

            f16x8 a00 = *(const f16x8*)&win[b00 + ((chunk ^ x7_00) * 8)];
            f16x8 a01 = *(const f16x8*)&win[b01 + ((chunk ^ x7_01) * 8)];
            f16x8 a10 = *(const f16x8*)&win[b10 + ((chunk ^ x7_10) * 8)];
            f16x8 a11 = *(const f16x8*)&win[b11 + ((chunk ^ x7_11) * 8)];

            // rare fallback: corner outside window (value zeroed if off-image)
            if (__builtin_expect(okk != 15, 0)) {
                if (!ok00) {
                    const int yc = min(max(y0, 0), H_ - 1), xc = min(max(x0, 0), W_ - 1);
                    const bool in = ((unsigned)y0 < H_) && ((unsigned)x0 < W_);
                    a00 = in ? *(const f16x8*)&xbT[((size_t)(yc * W_ + xc)) * 64 + c0] : splat8((_Float16)0.0f);
                }
                if (!ok01) {
                    const int yc = min(max(y0, 0), H_ - 1), xc = min(max(x0 + 1, 0), W_ - 1);
                    const bool in = ((unsigned)y0 < H_) && ((unsigned)(x0 + 1) < W_);
                    a01 = in ? *(const f16x8*)&xbT[((size_t)(yc * W_ + xc)) * 64 + c0] : splat8((_Float16)0.0f);
                }
                if (!ok10) {
                    const int yc = min(max(y0 + 1, 0), H_ - 1), xc = min(max(x0, 0), W_ - 1);
                    const bool in = ((unsigned)(y0 + 1) < H_) && ((unsigned)x0 < W_);
                    a10 = in ? *(const f16x8*)&xbT[((size_t)(yc * W_ + xc)) * 64 + c0] : splat8((_Float16)0.0f);
                }
                if (!ok11) {
                    const int yc = min(max(y0 + 1, 0), H_ - 1), xc = min(max(x0 + 1, 0), W_ - 1);
                    const bool in = ((unsigned)(y0 + 1) < H_) && ((unsigned)(x0 + 1) < W_);
                    a11 = in ? *(const f16x8*)&xbT[((size_t)(yc * W_ + xc)) * 64 + c0] : splat8((_Float16)0.0f);
                }
            }

            f16x8 r = a00 * w00v;
            r = a01 * w01v + r;
            r = a10 * w10v + r;
            r = a11 * w11v + r;

#pragma unroll
            for (int mt = 0; mt < 4; ++mt)
                acc[mt] = __builtin_amdgcn_mfma_f32_16x16x32_f16(af[mt], r, acc[mt], 0, 0, 0);
        }
    }

    // Epilogue B: D col = ln -> px, row = o.
    float* __restrict__ ob = out + (size_t)b * O_ * HW_ + (size_t)yo * W_;
#pragma unroll
    for (int mt = 0; mt < 4; ++mt)
#pragma unroll
        for (int r = 0; r < 4; ++r) {
            const int o = mt * 16 + lq * 4 + r;
            ob[(size_t)o * HW_ + wo] = acc[mt][r];
        }
}

extern "C" void kernel_launch(void* const* d_in, const int* in_sizes, int n_in,
                              void* d_out, int out_size, void* d_ws, size_t ws_size,
                              hipStream_t stream) {
    (void)in_sizes; (void)n_in; (void)out_size; (void)ws_size;
    const float* x    = (const float*)d_in[0];
    const float* offw = (const float*)d_in[1];
    const float* offb = (const float*)d_in[2];
    const float* modw = (const float*)d_in[3];
    const float* modb = (const float*)d_in[4];
    const float* wgt  = (const float*)d_in[5];
    float* out = (float*)d_out;

    _Float16* wpM = (_Float16*)d_ws;                                   // 73728 B
    _Float16* wpA = (_Float16*)((char*)d_ws + WPM_BYTES);              // 36864 B
    _Float16* xT  = (_Float16*)((char*)d_ws + WPM_BYTES + WPA_BYTES);  // 16.78 MB

    prep_kernel<<<TB2_ + 27, 256, 0, stream>>>(x, offw, modw, wgt, xT, wpM, wpA);
    dcn_main_kernel<<<B_ * H_ * 2, 256, 0, stream>>>(xT, wpA, wpM, offb, modb, out);
}

// Round 11
// 133.957 us; speedup vs baseline: 1.1591x; 1.0068x over previous
//
#include <hip/hip_runtime.h>
#include <math.h>

// Problem constants
#define B_   8
#define C_   64
#define O_   64
#define H_   128
#define W_   128
#define HW_  (H_ * W_)
#define KSZ  576            // C_*9 contraction length

typedef _Float16 f16x8 __attribute__((ext_vector_type(8)));
typedef float    f32x4 __attribute__((ext_vector_type(4)));

#define WPM_BYTES (18 * 4 * 64 * 8 * 2)   // 73728
#define WPA_BYTES (18 * 2 * 64 * 8 * 2)   // 36864
#define TB2_      (B_ * HW_ / 128)        // 1024 transpose tiles (128 px x 64 ch)

// ---------------------------------------------------------------------------
// Prep kernel (unchanged — vectorized transpose + weight prepack).
// ---------------------------------------------------------------------------
__global__ __launch_bounds__(256) void prep_kernel(
    const float* __restrict__ x,
    const float* __restrict__ offw, const float* __restrict__ modw,
    const float* __restrict__ wgt,
    _Float16* __restrict__ xT, _Float16* __restrict__ wpM, _Float16* __restrict__ wpA)
{
    const int bi = blockIdx.x;
    if (bi < TB2_) {
        __shared__ _Float16 tile[128 * 68];
        const int tid = threadIdx.x;
        const int b      = bi >> 7;
        const int pxbase = (bi & 127) * 128;

        const int px4   = (tid & 31) * 4;
        const int cbase = tid >> 5;
        const float* __restrict__ xp = x + (size_t)b * C_ * HW_ + pxbase;
#pragma unroll
        for (int r = 0; r < 8; ++r) {
            const int c = cbase + r * 8;
            const f32x4 v = *(const f32x4*)&xp[(size_t)c * HW_ + px4];
#pragma unroll
            for (int i = 0; i < 4; ++i)
                tile[(px4 + i) * 68 + c] = (_Float16)v[i];
        }
        __syncthreads();

        const int px = tid >> 1;
        const int c0 = (tid & 1) * 32;
        f16x8 w[4];
#pragma unroll
        for (int q = 0; q < 4; ++q)
#pragma unroll
            for (int j = 0; j < 8; ++j)
                w[q][j] = tile[px * 68 + c0 + q * 8 + j];
        _Float16* __restrict__ op = xT + ((size_t)b * HW_ + pxbase + px) * 64 + c0;
#pragma unroll
        for (int q = 0; q < 4; ++q)
            *(f16x8*)&op[q * 8] = w[q];
        return;
    }
    const int g = (bi - TB2_) * 256 + threadIdx.x;
    if (g < 18 * 4 * 64) {
        const int s = g >> 8, mt = (g >> 6) & 3, lane = g & 63;
        const int k = s >> 1, cb = (s & 1) * 32;
        const int o  = mt * 16 + (lane & 15);
        const int c0 = cb + (lane >> 4) * 8;
        f16x8 v;
#pragma unroll
        for (int j = 0; j < 8; ++j) v[j] = (_Float16)wgt[o * KSZ + (c0 + j) * 9 + k];
        *(f16x8*)&wpM[(size_t)g * 8] = v;
    } else if (g < 18 * 4 * 64 + 18 * 2 * 64) {
        const int u = g - 18 * 4 * 64;
        const int s = u >> 7, mt = (u >> 6) & 1, lane = u & 63;
        const int k = s >> 1, cb = (s & 1) * 32;
        const int t  = mt * 16 + (lane & 15);
        const int c0 = cb + (lane >> 4) * 8;
        f16x8 v;
#pragma unroll
        for (int j = 0; j < 8; ++j) {
            float w = 0.0f;
            if (t < 18)      w = offw[t * KSZ + (c0 + j) * 9 + k];
            else if (t < 27) w = modw[(t - 18) * KSZ + (c0 + j) * 9 + k];
            v[j] = (_Float16)w;
        }
        *(f16x8*)&wpA[(size_t)u * 8] = v;
    }
}

__device__ __forceinline__ f16x8 splat8(_Float16 h) {
    f16x8 v = {h, h, h, h, h, h, h, h};
    return v;
}

// ---------------------------------------------------------------------------
// Fused main kernel (v10 — params via LDS, shfl off the chain head).
// Ledger: v3=57.2, v7=60.0, v8=48.8, v9=47.3. v9 showed occupancy/staging
// exhausted (LDS 38.9K->31.0K, +1 blk/CU: only +3%; VALUBusy stuck ~50%).
// New model: per-k serial chain bpermute(120cy) -> tap math -> ds_read
// (120cy) -> combine -> MFMA, where bpermute and win-reads share lgkmcnt,
// so waiting on a shfl drains win-reads too — chains can't overlap.
// v10 replaces the 27 __shfl broadcasts with a params LDS array:
//   params[wrow][px 16][28] f32 (7KB; t-dim padded to 28 for b64 pairs).
//   Phase-A epilogue ds_writes it; phase-B reads own-px params at
//   COMPILE-TIME-CONSTANT offsets (4 lanes/addr broadcast, conflict-free),
//   so the compiler can issue all 18 loads early and fine-grain lgkmcnt.
//   All intra-wave (wave wrow owns params[wrow]) => no extra barrier.
// Cost: LDS 31.0->38.1KB (5->4 blocks/CU, worth <=1.5us per v9's A/B).
// Everything else byte-identical to v9.
// ---------------------------------------------------------------------------
#define WROWS 11
#define WCOLS 22

__global__ __launch_bounds__(256) void dcn_main_kernel(
    const _Float16* __restrict__ xT,    // (B, H, W, C) f16
    const _Float16* __restrict__ wpA,   // packed offset/mod weight frags
    const _Float16* __restrict__ wpM,   // packed main weight frags
    const float* __restrict__ offb,     // (18,)
    const float* __restrict__ modb,     // (9,)
    float* __restrict__ out)            // (B, O, H, W)
{
    __shared__ _Float16 win[WROWS * WCOLS * 64];   // 30976 B
    __shared__ float params[4][16][28];            // 7168 B  [wave][px][t]

    const int tid  = threadIdx.x;
    const int lane = tid & 63;
    const int wave = tid >> 6;
    const int lq   = lane >> 4;
    const int ln   = lane & 15;

    const int bi   = blockIdx.x;
    const int b    = bi & 7;            // XCD-pinned batch
    const int rest = bi >> 3;           // 0..255
    const int ho   = (rest >> 3) * 4;   // row-quad base (32 groups)
    const int x0b  = (rest & 7) * 16;   // col-sixteenth base (8 groups)

    const int wrow = wave;              // 0..3: output row ho+wrow
    const int yo   = ho + wrow;         // this wave's output row
    const int pxw  = ln;                // px within 16-col tile
    const int wo   = x0b + pxw;         // this lane's output x

    const _Float16* __restrict__ xbT = xT + (size_t)b * HW_ * 64;

    // ---------------- Stage window (ZERO-padded): rows ho-3..ho+7, ---------
    // cols x0b-3..x0b+18.  11*22*8 = 1936 chunk-slots.
#pragma unroll
    for (int it = 0; it < 8; ++it) {
        const int e = it * 256 + tid;
        if (e < WROWS * WCOLS * 8) {
            const int r   = e / (WCOLS * 8);
            const int rem = e - r * (WCOLS * 8);
            const int cx  = rem >> 3;
            const int q   = rem & 7;
            const int yr  = ho - 3 + r;
            const int xc  = x0b - 3 + cx;
            f16x8 v = splat8((_Float16)0.0f);
            if (((unsigned)yr < H_) && ((unsigned)xc < W_))
                v = *(const f16x8*)&xbT[((size_t)(yr * W_ + xc)) * 64 + q * 8];
            *(f16x8*)&win[(r * WCOLS + cx) * 64 + ((q ^ (cx & 7)) * 8)] = v;
        }
    }
    __syncthreads();

    // ---------------- Phase A: offset/modulator conv via MFMA (no branches)
    f32x4 accA[2];
#pragma unroll
    for (int mt = 0; mt < 2; ++mt) accA[mt] = (f32x4){0.f, 0.f, 0.f, 0.f};

#pragma unroll
    for (int s = 0; s < 18; ++s) {
        const int k = s >> 1, h = s & 1;
        const int ki = k / 3, kj = k - ki * 3;
        f16x8 afA[2];
#pragma unroll
        for (int mt = 0; mt < 2; ++mt)
            afA[mt] = *(const f16x8*)&wpA[(size_t)((s * 2 + mt) * 64 + lane) * 8];
        const int sy = wrow + ki + 2;        // row (yo-1+ki) rel to ho-3
        const int sx = pxw + kj + 2;         // col (wo-1+kj) rel to x0b-3
        const int chunk = h * 4 + lq;
        const f16x8 bfA = *(const f16x8*)&win[(sy * WCOLS + sx) * 64 + ((chunk ^ (sx & 7)) * 8)];
#pragma unroll
        for (int mt = 0; mt < 2; ++mt)
            accA[mt] = __builtin_amdgcn_mfma_f32_16x16x32_f16(afA[mt], bfA, accA[mt], 0, 0, 0);
    }

    // Epilogue A: lane (lq,ln) owns t = mt*16 + lq*4 + r for px ln.
    // Write straight to the params LDS (intra-wave producer/consumer; the
    // compiler's lgkmcnt tracking orders writes before the phase-B reads —
    // no barrier needed, all traffic stays inside wave wrow's slice).
#pragma unroll
    for (int mt = 0; mt < 2; ++mt)
#pragma unroll
        for (int r = 0; r < 4; ++r) {
            const int t = mt * 16 + lq * 4 + r;
            const float val = accA[mt][r];
            if (t < 18)      params[wrow][ln][t] = val + offb[t];
            else if (t < 27) params[wrow][ln][t] = 2.0f / (1.0f + expf(-(val + modb[t - 18])));
        }

    // ---------------- Phase B: deformable gather (LDS) + MFMA --------------
    f32x4 acc[4];
#pragma unroll
    for (int mt = 0; mt < 4; ++mt) acc[mt] = (f32x4){0.f, 0.f, 0.f, 0.f};

#pragma unroll
    for (int k = 0; k < 9; ++k) {
        const int ki = k / 3, kj = k - ki * 3;

        // own-px params at compile-time-constant LDS offsets (broadcast read)
        const float dy = params[wrow][ln][2 * k];
        const float dx = params[wrow][ln][2 * k + 1];
        const float mk = params[wrow][ln][18 + k];

        const float ys = (float)(yo - 1 + ki) + dy;
        const float xs = (float)(wo - 1 + kj) + dx;
        const float y0f = floorf(ys), x0f = floorf(xs);
        const float wy = ys - y0f, wx = xs - x0f;
        const int y0 = (int)y0f, x0 = (int)x0f;
        const float wyc = 1.0f - wy, wxc = 1.0f - wx;
        const float w00 = wyc * wxc * mk;
        const float w01 = wyc * wx  * mk;
        const float w10 = wy  * wxc * mk;
        const float w11 = wy  * wx  * mk;

        // window slots from RAW coords (zero-pad makes raw lookup correct)
        const int sy0 = y0 - ho + 3, sy1 = sy0 + 1;
        const int sx0 = x0 - x0b + 3, sx1 = sx0 + 1;
        const int ok00 = ((unsigned)sy0 < WROWS) & ((unsigned)sx0 < WCOLS);
        const int ok01 = ((unsigned)sy0 < WROWS) & ((unsigned)sx1 < WCOLS);
        const int ok10 = ((unsigned)sy1 < WROWS) & ((unsigned)sx0 < WCOLS);
        const int ok11 = ((unsigned)sy1 < WROWS) & ((unsigned)sx1 < WCOLS);
        const int okk  = ok00 | (ok01 << 1) | (ok10 << 2) | (ok11 << 3);
        // safe (in-window) slots for the LDS address; fallback overrides
        const int cy0 = min(max(sy0, 0), WROWS - 1), cy1 = min(max(sy1, 0), WROWS - 1);
        const int cx0 = min(max(sx0, 0), WCOLS - 1), cx1 = min(max(sx1, 0), WCOLS - 1);
        const int b00 = (cy0 * WCOLS + cx0) * 64, x7_00 = cx0 & 7;
        const int b01 = (cy0 * WCOLS + cx1) * 64, x7_01 = cx1 & 7;
        const int b10 = (cy1 * WCOLS + cx0) * 64, x7_10 = cx0 & 7;
        const int b11 = (cy1 * WCOLS + cx1) * 64, x7_11 = cx1 & 7;

        const f16x8 w00v = splat8((_Float16)w00);
        const f16x8 w01v = splat8((_Float16)w01);
        const f16x8 w10v = splat8((_Float16)w10);
        const f16x8 w11v = splat8((_Float16)w11);

#pragma unroll
        for (int h = 0; h < 2; ++h) {
            const int s = 2 * k + h;
            const int chunk = h * 4 + lq;
            const int c0 = h * 32 + lq * 8;

            f16x8 af[4];
#pragma unroll
            for (int mt = 0; mt < 4; ++mt)
                af[mt] = *(const f16x8*)&wpM[(size_t)((s * 4 + mt) * 64 + lane) * 8];

            f16x8 a00 = *(const f16x8*)&win[b00 + ((chunk ^ x7_00) * 8)];
            f16x8 a01 = *(const f16x8*)&win[b01 + ((chunk ^ x7_01) * 8)];
            f16x8 a10 = *(const f16x8*)&win[b10 + ((chunk ^ x7_10) * 8)];
            f16x8 a11 = *(const f16x8*)&win[b11 + ((chunk ^ x7_11) * 8)];

            // rare fallback: corner outside window (value zeroed if off-image)
            if (__builtin_expect(okk != 15, 0)) {
                if (!ok00) {
                    const int yc = min(max(y0, 0), H_ - 1), xc = min(max(x0, 0), W_ - 1);
                    const bool in = ((unsigned)y0 < H_) && ((unsigned)x0 < W_);
                    a00 = in ? *(const f16x8*)&xbT[((size_t)(yc * W_ + xc)) * 64 + c0] : splat8((_Float16)0.0f);
                }
                if (!ok01) {
                    const int yc = min(max(y0, 0), H_ - 1), xc = min(max(x0 + 1, 0), W_ - 1);
                    const bool in = ((unsigned)y0 < H_) && ((unsigned)(x0 + 1) < W_);
                    a01 = in ? *(const f16x8*)&xbT[((size_t)(yc * W_ + xc)) * 64 + c0] : splat8((_Float16)0.0f);
                }
                if (!ok10) {
                    const int yc = min(max(y0 + 1, 0), H_ - 1), xc = min(max(x0, 0), W_ - 1);
                    const bool in = ((unsigned)(y0 + 1) < H_) && ((unsigned)x0 < W_);
                    a10 = in ? *(const f16x8*)&xbT[((size_t)(yc * W_ + xc)) * 64 + c0] : splat8((_Float16)0.0f);
                }
                if (!ok11) {
                    const int yc = min(max(y0 + 1, 0), H_ - 1), xc = min(max(x0 + 1, 0), W_ - 1);
                    const bool in = ((unsigned)(y0 + 1) < H_) && ((unsigned)(x0 + 1) < W_);
                    a11 = in ? *(const f16x8*)&xbT[((size_t)(yc * W_ + xc)) * 64 + c0] : splat8((_Float16)0.0f);
                }
            }

            f16x8 r = a00 * w00v;
            r = a01 * w01v + r;
            r = a10 * w10v + r;
            r = a11 * w11v + r;

#pragma unroll
            for (int mt = 0; mt < 4; ++mt)
                acc[mt] = __builtin_amdgcn_mfma_f32_16x16x32_f16(af[mt], r, acc[mt], 0, 0, 0);
        }
    }

    // Epilogue B: D col = ln -> px, row = o.
    float* __restrict__ ob = out + (size_t)b * O_ * HW_ + (size_t)yo * W_;
#pragma unroll
    for (int mt = 0; mt < 4; ++mt)
#pragma unroll
        for (int r = 0; r < 4; ++r) {
            const int o = mt * 16 + lq * 4 + r;
            ob[(size_t)o * HW_ + wo] = acc[mt][r];
        }
}

extern "C" void kernel_launch(void* const* d_in, const int* in_sizes, int n_in,
                              void* d_out, int out_size, void* d_ws, size_t ws_size,
                              hipStream_t stream) {
    (void)in_sizes; (void)n_in; (void)out_size; (void)ws_size;
    const float* x    = (const float*)d_in[0];
    const float* offw = (const float*)d_in[1];
    const float* offb = (const float*)d_in[2];
    const float* modw = (const float*)d_in[3];
    const float* modb = (const float*)d_in[4];
    const float* wgt  = (const float*)d_in[5];
    float* out = (float*)d_out;

    _Float16* wpM = (_Float16*)d_ws;                                   // 73728 B
    _Float16* wpA = (_Float16*)((char*)d_ws + WPM_BYTES);              // 36864 B
    _Float16* xT  = (_Float16*)((char*)d_ws + WPM_BYTES + WPA_BYTES);  // 16.78 MB

    prep_kernel<<<TB2_ + 27, 256, 0, stream>>>(x, offw, modw, wgt, xT, wpM, wpA);
    dcn_main_kernel<<<B_ * H_ * 2, 256, 0, stream>>>(xT, wpA, wpM, offb, modb, out);
}

// Round 12
// 133.415 us; speedup vs baseline: 1.1638x; 1.0041x over previous
//
#include <hip/hip_runtime.h>
#include <math.h>

// Problem constants
#define B_   8
#define C_   64
#define O_   64
#define H_   128
#define W_   128
#define HW_  (H_ * W_)
#define KSZ  576            // C_*9 contraction length

typedef _Float16 f16x8 __attribute__((ext_vector_type(8)));
typedef float    f32x4 __attribute__((ext_vector_type(4)));

#define WPM_BYTES (18 * 4 * 64 * 8 * 2)   // 73728
#define WPA_BYTES (18 * 2 * 64 * 8 * 2)   // 36864
#define TB2_      (B_ * HW_ / 128)        // 1024 transpose tiles (128 px x 64 ch)

// ---------------------------------------------------------------------------
// Prep kernel (unchanged — vectorized transpose + weight prepack).
// ---------------------------------------------------------------------------
__global__ __launch_bounds__(256) void prep_kernel(
    const float* __restrict__ x,
    const float* __restrict__ offw, const float* __restrict__ modw,
    const float* __restrict__ wgt,
    _Float16* __restrict__ xT, _Float16* __restrict__ wpM, _Float16* __restrict__ wpA)
{
    const int bi = blockIdx.x;
    if (bi < TB2_) {
        __shared__ _Float16 tile[128 * 68];
        const int tid = threadIdx.x;
        const int b      = bi >> 7;
        const int pxbase = (bi & 127) * 128;

        const int px4   = (tid & 31) * 4;
        const int cbase = tid >> 5;
        const float* __restrict__ xp = x + (size_t)b * C_ * HW_ + pxbase;
#pragma unroll
        for (int r = 0; r < 8; ++r) {
            const int c = cbase + r * 8;
            const f32x4 v = *(const f32x4*)&xp[(size_t)c * HW_ + px4];
#pragma unroll
            for (int i = 0; i < 4; ++i)
                tile[(px4 + i) * 68 + c] = (_Float16)v[i];
        }
        __syncthreads();

        const int px = tid >> 1;
        const int c0 = (tid & 1) * 32;
        f16x8 w[4];
#pragma unroll
        for (int q = 0; q < 4; ++q)
#pragma unroll
            for (int j = 0; j < 8; ++j)
                w[q][j] = tile[px * 68 + c0 + q * 8 + j];
        _Float16* __restrict__ op = xT + ((size_t)b * HW_ + pxbase + px) * 64 + c0;
#pragma unroll
        for (int q = 0; q < 4; ++q)
            *(f16x8*)&op[q * 8] = w[q];
        return;
    }
    const int g = (bi - TB2_) * 256 + threadIdx.x;
    if (g < 18 * 4 * 64) {
        const int s = g >> 8, mt = (g >> 6) & 3, lane = g & 63;
        const int k = s >> 1, cb = (s & 1) * 32;
        const int o  = mt * 16 + (lane & 15);
        const int c0 = cb + (lane >> 4) * 8;
        f16x8 v;
#pragma unroll
        for (int j = 0; j < 8; ++j) v[j] = (_Float16)wgt[o * KSZ + (c0 + j) * 9 + k];
        *(f16x8*)&wpM[(size_t)g * 8] = v;
    } else if (g < 18 * 4 * 64 + 18 * 2 * 64) {
        const int u = g - 18 * 4 * 64;
        const int s = u >> 7, mt = (u >> 6) & 1, lane = u & 63;
        const int k = s >> 1, cb = (s & 1) * 32;
        const int t  = mt * 16 + (lane & 15);
        const int c0 = cb + (lane >> 4) * 8;
        f16x8 v;
#pragma unroll
        for (int j = 0; j < 8; ++j) {
            float w = 0.0f;
            if (t < 18)      w = offw[t * KSZ + (c0 + j) * 9 + k];
            else if (t < 27) w = modw[(t - 18) * KSZ + (c0 + j) * 9 + k];
            v[j] = (_Float16)w;
        }
        *(f16x8*)&wpA[(size_t)u * 8] = v;
    }
}

__device__ __forceinline__ f16x8 splat8(_Float16 h) {
    f16x8 v = {h, h, h, h, h, h, h, h};
    return v;
}

// ---------------------------------------------------------------------------
// Fused main kernel (v11 — explicit 1-deep tap pipeline; only delta vs v10).
// Ledger: v8=48.8, v9=47.3, v10=45.4. Corrected-counter model: per-SIMD
// VALU ~20%, LDS pipe ~30-40%, MFMA ~3% => ~60% dependency stall; VGPR=64
// shows the compiler scheduled for min-pressure, no cross-tap overlap.
// v11 software-pipelines taps 1 deep:
//   STAGE(k): params read + tap math + corner addrs + issue 4 h0 ds_reads.
//   CONSUME(k): issue 4 h1 ds_reads (elem^32), rare fallback fix (both
//   halves), then combine+MFMA h0 (hides h1 latency), combine+MFMA h1.
//   STAGE(k+1) executes before CONSUME(k) -> k+1's reads fill under k's
//   combine. State in pa/pe/pw/pok parity arrays, literal (k&1) indices in
//   a fully-unrolled loop (static — no scratch). ~+50 VGPR, free: LDS
//   38.4KB caps residency at 4 blocks/CU, fine up to 128 VGPR.
// Failure tells: VGPR stays ~64 => compiler re-sank (flat); VGPR>128 =>
// occupancy drop (revert).
// ---------------------------------------------------------------------------
#define WROWS 11
#define WCOLS 22

__global__ __launch_bounds__(256) void dcn_main_kernel(
    const _Float16* __restrict__ xT,    // (B, H, W, C) f16
    const _Float16* __restrict__ wpA,   // packed offset/mod weight frags
    const _Float16* __restrict__ wpM,   // packed main weight frags
    const float* __restrict__ offb,     // (18,)
    const float* __restrict__ modb,     // (9,)
    float* __restrict__ out)            // (B, O, H, W)
{
    __shared__ _Float16 win[WROWS * WCOLS * 64];   // 30976 B
    __shared__ float params[4][16][28];            // 7168 B  [wave][px][t]

    const int tid  = threadIdx.x;
    const int lane = tid & 63;
    const int wave = tid >> 6;
    const int lq   = lane >> 4;
    const int ln   = lane & 15;

    const int bi   = blockIdx.x;
    const int b    = bi & 7;            // XCD-pinned batch
    const int rest = bi >> 3;           // 0..255
    const int ho   = (rest >> 3) * 4;   // row-quad base (32 groups)
    const int x0b  = (rest & 7) * 16;   // col-sixteenth base (8 groups)

    const int wrow = wave;              // 0..3: output row ho+wrow
    const int yo   = ho + wrow;         // this wave's output row
    const int pxw  = ln;                // px within 16-col tile
    const int wo   = x0b + pxw;         // this lane's output x

    const _Float16* __restrict__ xbT = xT + (size_t)b * HW_ * 64;

    // ---------------- Stage window (ZERO-padded): rows ho-3..ho+7, ---------
    // cols x0b-3..x0b+18.  11*22*8 = 1936 chunk-slots.
#pragma unroll
    for (int it = 0; it < 8; ++it) {
        const int e = it * 256 + tid;
        if (e < WROWS * WCOLS * 8) {
            const int r   = e / (WCOLS * 8);
            const int rem = e - r * (WCOLS * 8);
            const int cx  = rem >> 3;
            const int q   = rem & 7;
            const int yr  = ho - 3 + r;
            const int xc  = x0b - 3 + cx;
            f16x8 v = splat8((_Float16)0.0f);
            if (((unsigned)yr < H_) && ((unsigned)xc < W_))
                v = *(const f16x8*)&xbT[((size_t)(yr * W_ + xc)) * 64 + q * 8];
            *(f16x8*)&win[(r * WCOLS + cx) * 64 + ((q ^ (cx & 7)) * 8)] = v;
        }
    }
    __syncthreads();

    // ---------------- Phase A: offset/modulator conv via MFMA (no branches)
    f32x4 accA[2];
#pragma unroll
    for (int mt = 0; mt < 2; ++mt) accA[mt] = (f32x4){0.f, 0.f, 0.f, 0.f};

#pragma unroll
    for (int s = 0; s < 18; ++s) {
        const int k = s >> 1, h = s & 1;
        const int ki = k / 3, kj = k - ki * 3;
        f16x8 afA[2];
#pragma unroll
        for (int mt = 0; mt < 2; ++mt)
            afA[mt] = *(const f16x8*)&wpA[(size_t)((s * 2 + mt) * 64 + lane) * 8];
        const int sy = wrow + ki + 2;        // row (yo-1+ki) rel to ho-3
        const int sx = pxw + kj + 2;         // col (wo-1+kj) rel to x0b-3
        const int chunk = h * 4 + lq;
        const f16x8 bfA = *(const f16x8*)&win[(sy * WCOLS + sx) * 64 + ((chunk ^ (sx & 7)) * 8)];
#pragma unroll
        for (int mt = 0; mt < 2; ++mt)
            accA[mt] = __builtin_amdgcn_mfma_f32_16x16x32_f16(afA[mt], bfA, accA[mt], 0, 0, 0);
    }

    // Epilogue A: lane (lq,ln) owns t = mt*16 + lq*4 + r for px ln.
    // Intra-wave producer/consumer via LDS; lgkmcnt orders it, no barrier.
#pragma unroll
    for (int mt = 0; mt < 2; ++mt)
#pragma unroll
        for (int r = 0; r < 4; ++r) {
            const int t = mt * 16 + lq * 4 + r;
            const float val = accA[mt][r];
            if (t < 18)      params[wrow][ln][t] = val + offb[t];
            else if (t < 27) params[wrow][ln][t] = 2.0f / (1.0f + expf(-(val + modb[t - 18])));
        }

    // ---------------- Phase B: 1-deep pipelined gather + MFMA --------------
    f32x4 acc[4];
#pragma unroll
    for (int mt = 0; mt < 4; ++mt) acc[mt] = (f32x4){0.f, 0.f, 0.f, 0.f};

    f16x8 pa[2][4];     // h0 corner data per parity
    int   pe[2][4];     // corner elem offsets (h1 = e ^ 32)
    float pw[2][4];     // bilinear*mask weights
    int   pok[2], py0[2], px0[2];

#define FIXC(av, bv, yy, xx) do {                                             \
        const int yc_ = min(max((yy), 0), H_ - 1);                            \
        const int xc_ = min(max((xx), 0), W_ - 1);                            \
        const bool in_ = ((unsigned)(yy) < H_) && ((unsigned)(xx) < W_);      \
        const _Float16* fp_ = &xbT[((size_t)(yc_ * W_ + xc_)) * 64 + lq * 8]; \
        (av) = in_ ? *(const f16x8*)&fp_[0]  : splat8((_Float16)0.0f);        \
        (bv) = in_ ? *(const f16x8*)&fp_[32] : splat8((_Float16)0.0f);        \
    } while (0)

#define TAPSTAGE(kk, par) do {                                                \
        const int ki_ = (kk) / 3, kj_ = (kk) - ki_ * 3;                       \
        const float dy_ = params[wrow][ln][2 * (kk)];                         \
        const float dx_ = params[wrow][ln][2 * (kk) + 1];                     \
        const float mk_ = params[wrow][ln][18 + (kk)];                        \
        const float ys_ = (float)(yo - 1 + ki_) + dy_;                        \
        const float xs_ = (float)(wo - 1 + kj_) + dx_;                        \
        const float y0f_ = floorf(ys_), x0f_ = floorf(xs_);                   \
        const float wy_ = ys_ - y0f_, wx_ = xs_ - x0f_;                       \
        const int y0_ = (int)y0f_, x0_ = (int)x0f_;                           \
        const float wyc_ = 1.0f - wy_, wxc_ = 1.0f - wx_;                     \
        pw[par][0] = wyc_ * wxc_ * mk_;                                       \
        pw[par][1] = wyc_ * wx_  * mk_;                                       \
        pw[par][2] = wy_  * wxc_ * mk_;                                       \
        pw[par][3] = wy_  * wx_  * mk_;                                       \
        const int sy0_ = y0_ - ho + 3, sy1_ = sy0_ + 1;                       \
        const int sx0_ = x0_ - x0b + 3, sx1_ = sx0_ + 1;                      \
        const int o00_ = ((unsigned)sy0_ < WROWS) & ((unsigned)sx0_ < WCOLS); \
        const int o01_ = ((unsigned)sy0_ < WROWS) & ((unsigned)sx1_ < WCOLS); \
        const int o10_ = ((unsigned)sy1_ < WROWS) & ((unsigned)sx0_ < WCOLS); \
        const int o11_ = ((unsigned)sy1_ < WROWS) & ((unsigned)sx1_ < WCOLS); \
        pok[par] = o00_ | (o01_ << 1) | (o10_ << 2) | (o11_ << 3);            \
        py0[par] = y0_; px0[par] = x0_;                                       \
        const int cy0_ = min(max(sy0_, 0), WROWS - 1);                        \
        const int cy1_ = min(max(sy1_, 0), WROWS - 1);                        \
        const int cx0_ = min(max(sx0_, 0), WCOLS - 1);                        \
        const int cx1_ = min(max(sx1_, 0), WCOLS - 1);                        \
        const int x70_ = cx0_ & 7, x71_ = cx1_ & 7;                           \
        pe[par][0] = (cy0_ * WCOLS + cx0_) * 64 + ((lq ^ x70_) * 8);          \
        pe[par][1] = (cy0_ * WCOLS + cx1_) * 64 + ((lq ^ x71_) * 8);          \
        pe[par][2] = (cy1_ * WCOLS + cx0_) * 64 + ((lq ^ x70_) * 8);          \
        pe[par][3] = (cy1_ * WCOLS + cx1_) * 64 + ((lq ^ x71_) * 8);          \
        pa[par][0] = *(const f16x8*)&win[pe[par][0]];                         \
        pa[par][1] = *(const f16x8*)&win[pe[par][1]];                         \
        pa[par][2] = *(const f16x8*)&win[pe[par][2]];                         \
        pa[par][3] = *(const f16x8*)&win[pe[par][3]];                         \
    } while (0)

#define CONSUME(kk, par) do {                                                 \
        f16x8 b0_ = *(const f16x8*)&win[pe[par][0] ^ 32];                     \
        f16x8 b1_ = *(const f16x8*)&win[pe[par][1] ^ 32];                     \
        f16x8 b2_ = *(const f16x8*)&win[pe[par][2] ^ 32];                     \
        f16x8 b3_ = *(const f16x8*)&win[pe[par][3] ^ 32];                     \
        f16x8 a0_ = pa[par][0], a1_ = pa[par][1];                             \
        f16x8 a2_ = pa[par][2], a3_ = pa[par][3];                             \
        const int okk_ = pok[par];                                            \
        if (__builtin_expect(okk_ != 15, 0)) {                                \
            const int y0_ = py0[par], x0_ = px0[par];                         \
            if (!(okk_ & 1)) FIXC(a0_, b0_, y0_,     x0_);                    \
            if (!(okk_ & 2)) FIXC(a1_, b1_, y0_,     x0_ + 1);                \
            if (!(okk_ & 4)) FIXC(a2_, b2_, y0_ + 1, x0_);                    \
            if (!(okk_ & 8)) FIXC(a3_, b3_, y0_ + 1, x0_ + 1);                \
        }                                                                     \
        const f16x8 w0_ = splat8((_Float16)pw[par][0]);                       \
        const f16x8 w1_ = splat8((_Float16)pw[par][1]);                       \
        const f16x8 w2_ = splat8((_Float16)pw[par][2]);                       \
        const f16x8 w3_ = splat8((_Float16)pw[par][3]);                       \
        {                                                                     \
            const int s_ = 2 * (kk);                                          \
            f16x8 af0_ = *(const f16x8*)&wpM[(size_t)((s_ * 4 + 0) * 64 + lane) * 8]; \
            f16x8 af1_ = *(const f16x8*)&wpM[(size_t)((s_ * 4 + 1) * 64 + lane) * 8]; \
            f16x8 af2_ = *(const f16x8*)&wpM[(size_t)((s_ * 4 + 2) * 64 + lane) * 8]; \
            f16x8 af3_ = *(const f16x8*)&wpM[(size_t)((s_ * 4 + 3) * 64 + lane) * 8]; \
            f16x8 r_ = a0_ * w0_;                                             \
            r_ = a1_ * w1_ + r_;                                              \
            r_ = a2_ * w2_ + r_;                                              \
            r_ = a3_ * w3_ + r_;                                              \
            acc[0] = __builtin_amdgcn_mfma_f32_16x16x32_f16(af0_, r_, acc[0], 0, 0, 0); \
            acc[1] = __builtin_amdgcn_mfma_f32_16x16x32_f16(af1_, r_, acc[1], 0, 0, 0); \
            acc[2] = __builtin_amdgcn_mfma_f32_16x16x32_f16(af2_, r_, acc[2], 0, 0, 0); \
            acc[3] = __builtin_amdgcn_mfma_f32_16x16x32_f16(af3_, r_, acc[3], 0, 0, 0); \
        }                                                                     \
        {                                                                     \
            const int s_ = 2 * (kk) + 1;                                      \
            f16x8 af0_ = *(const f16x8*)&wpM[(size_t)((s_ * 4 + 0) * 64 + lane) * 8]; \
            f16x8 af1_ = *(const f16x8*)&wpM[(size_t)((s_ * 4 + 1) * 64 + lane) * 8]; \
            f16x8 af2_ = *(const f16x8*)&wpM[(size_t)((s_ * 4 + 2) * 64 + lane) * 8]; \
            f16x8 af3_ = *(const f16x8*)&wpM[(size_t)((s_ * 4 + 3) * 64 + lane) * 8]; \
            f16x8 r_ = b0_ * w0_;                                             \
            r_ = b1_ * w1_ + r_;                                              \
            r_ = b2_ * w2_ + r_;                                              \
            r_ = b3_ * w3_ + r_;                                              \
            acc[0] = __builtin_amdgcn_mfma_f32_16x16x32_f16(af0_, r_, acc[0], 0, 0, 0); \
            acc[1] = __builtin_amdgcn_mfma_f32_16x16x32_f16(af1_, r_, acc[1], 0, 0, 0); \
            acc[2] = __builtin_amdgcn_mfma_f32_16x16x32_f16(af2_, r_, acc[2], 0, 0, 0); \
            acc[3] = __builtin_amdgcn_mfma_f32_16x16x32_f16(af3_, r_, acc[3], 0, 0, 0); \
        }                                                                     \
    } while (0)

    TAPSTAGE(0, 0);
#pragma unroll
    for (int k = 1; k < 9; ++k) {
        if (k & 1) { TAPSTAGE(k, 1); CONSUME(k - 1, 0); }
        else       { TAPSTAGE(k, 0); CONSUME(k - 1, 1); }
    }
    CONSUME(8, 0);

#undef CONSUME
#undef TAPSTAGE
#undef FIXC

    // Epilogue B: D col = ln -> px, row = o.
    float* __restrict__ ob = out + (size_t)b * O_ * HW_ + (size_t)yo * W_;
#pragma unroll
    for (int mt = 0; mt < 4; ++mt)
#pragma unroll
        for (int r = 0; r < 4; ++r) {
            const int o = mt * 16 + lq * 4 + r;
            ob[(size_t)o * HW_ + wo] = acc[mt][r];
        }
}

extern "C" void kernel_launch(void* const* d_in, const int* in_sizes, int n_in,
                              void* d_out, int out_size, void* d_ws, size_t ws_size,
                              hipStream_t stream) {
    (void)in_sizes; (void)n_in; (void)out_size; (void)ws_size;
    const float* x    = (const float*)d_in[0];
    const float* offw = (const float*)d_in[1];
    const float* offb = (const float*)d_in[2];
    const float* modw = (const float*)d_in[3];
    const float* modb = (const float*)d_in[4];
    const float* wgt  = (const float*)d_in[5];
    float* out = (float*)d_out;

    _Float16* wpM = (_Float16*)d_ws;                                   // 73728 B
    _Float16* wpA = (_Float16*)((char*)d_ws + WPM_BYTES);              // 36864 B
    _Float16* xT  = (_Float16*)((char*)d_ws + WPM_BYTES + WPA_BYTES);  // 16.78 MB

    prep_kernel<<<TB2_ + 27, 256, 0, stream>>>(x, offw, modw, wgt, xT, wpM, wpA);
    dcn_main_kernel<<<B_ * H_ * 2, 256, 0, stream>>>(xT, wpA, wpM, offb, modb, out);
}

// Round 13
// 133.388 us; speedup vs baseline: 1.1640x; 1.0002x over previous
//
#include <hip/hip_runtime.h>
#include <math.h>

// Problem constants
#define B_   8
#define C_   64
#define O_   64
#define H_   128
#define W_   128
#define HW_  (H_ * W_)
#define KSZ  576            // C_*9 contraction length

typedef _Float16 f16x8 __attribute__((ext_vector_type(8)));
typedef float    f32x4 __attribute__((ext_vector_type(4)));

#define WPM_BYTES (18 * 4 * 64 * 8 * 2)   // 73728
#define WPA_BYTES (18 * 2 * 64 * 8 * 2)   // 36864
#define TB2_      (B_ * HW_ / 128)        // 1024 transpose tiles (128 px x 64 ch)

// ---------------------------------------------------------------------------
// Prep kernel (unchanged — vectorized transpose + weight prepack).
// ---------------------------------------------------------------------------
__global__ __launch_bounds__(256) void prep_kernel(
    const float* __restrict__ x,
    const float* __restrict__ offw, const float* __restrict__ modw,
    const float* __restrict__ wgt,
    _Float16* __restrict__ xT, _Float16* __restrict__ wpM, _Float16* __restrict__ wpA)
{
    const int bi = blockIdx.x;
    if (bi < TB2_) {
        __shared__ _Float16 tile[128 * 68];
        const int tid = threadIdx.x;
        const int b      = bi >> 7;
        const int pxbase = (bi & 127) * 128;

        const int px4   = (tid & 31) * 4;
        const int cbase = tid >> 5;
        const float* __restrict__ xp = x + (size_t)b * C_ * HW_ + pxbase;
#pragma unroll
        for (int r = 0; r < 8; ++r) {
            const int c = cbase + r * 8;
            const f32x4 v = *(const f32x4*)&xp[(size_t)c * HW_ + px4];
#pragma unroll
            for (int i = 0; i < 4; ++i)
                tile[(px4 + i) * 68 + c] = (_Float16)v[i];
        }
        __syncthreads();

        const int px = tid >> 1;
        const int c0 = (tid & 1) * 32;
        f16x8 w[4];
#pragma unroll
        for (int q = 0; q < 4; ++q)
#pragma unroll
            for (int j = 0; j < 8; ++j)
                w[q][j] = tile[px * 68 + c0 + q * 8 + j];
        _Float16* __restrict__ op = xT + ((size_t)b * HW_ + pxbase + px) * 64 + c0;
#pragma unroll
        for (int q = 0; q < 4; ++q)
            *(f16x8*)&op[q * 8] = w[q];
        return;
    }
    const int g = (bi - TB2_) * 256 + threadIdx.x;
    if (g < 18 * 4 * 64) {
        const int s = g >> 8, mt = (g >> 6) & 3, lane = g & 63;
        const int k = s >> 1, cb = (s & 1) * 32;
        const int o  = mt * 16 + (lane & 15);
        const int c0 = cb + (lane >> 4) * 8;
        f16x8 v;
#pragma unroll
        for (int j = 0; j < 8; ++j) v[j] = (_Float16)wgt[o * KSZ + (c0 + j) * 9 + k];
        *(f16x8*)&wpM[(size_t)g * 8] = v;
    } else if (g < 18 * 4 * 64 + 18 * 2 * 64) {
        const int u = g - 18 * 4 * 64;
        const int s = u >> 7, mt = (u >> 6) & 1, lane = u & 63;
        const int k = s >> 1, cb = (s & 1) * 32;
        const int t  = mt * 16 + (lane & 15);
        const int c0 = cb + (lane >> 4) * 8;
        f16x8 v;
#pragma unroll
        for (int j = 0; j < 8; ++j) {
            float w = 0.0f;
            if (t < 18)      w = offw[t * KSZ + (c0 + j) * 9 + k];
            else if (t < 27) w = modw[(t - 18) * KSZ + (c0 + j) * 9 + k];
            v[j] = (_Float16)w;
        }
        *(f16x8*)&wpA[(size_t)u * 8] = v;
    }
}

__device__ __forceinline__ f16x8 splat8(_Float16 h) {
    f16x8 v = {h, h, h, h, h, h, h, h};
    return v;
}

// ---------------------------------------------------------------------------
// Fused main kernel (v12 = v10 revert — best measured: 45.4us main).
// Ledger: v3=57.2, v7=60.0, v8=48.8 (2x32 tile), v9=47.3 (4x16 tile),
// v10=45.4 (params via LDS), v11=46.3 (explicit 1-deep pipeline: REGRESSED
// — VGPR 64->80, VALUBusy 52->43, occupancy 31->24; compiler's implicit
// wave-level overlap already covers what source pipelining expresses).
// v12 deletes the pipeline and restores v10 byte-identical:
//   4x16-px block, 11x22 window (zero-padded, XOR-swizzled), params in
//   LDS [wave][px][28] (shfl off the chain head), inline per-k phase B.
// Remaining accounting at 45.4us: LDS pipe ~21us + 4us conflicts, VALU
// ~7us, MFMA ~2us, staging ~3us -> within ~15-20% of the structure's
// mixed-pipe floor; corner-read volume and combine VALU are algorithmic
// minimums at this precision (absmax sits exactly at the 2^-6 threshold).
// Residual (total-main) = 85-89us across 8 measurements and 2 prep
// rewrites -> fixed harness overhead, not kernel-addressable.
// ---------------------------------------------------------------------------
#define WROWS 11
#define WCOLS 22

__global__ __launch_bounds__(256) void dcn_main_kernel(
    const _Float16* __restrict__ xT,    // (B, H, W, C) f16
    const _Float16* __restrict__ wpA,   // packed offset/mod weight frags
    const _Float16* __restrict__ wpM,   // packed main weight frags
    const float* __restrict__ offb,     // (18,)
    const float* __restrict__ modb,     // (9,)
    float* __restrict__ out)            // (B, O, H, W)
{
    __shared__ _Float16 win[WROWS * WCOLS * 64];   // 30976 B
    __shared__ float params[4][16][28];            // 7168 B  [wave][px][t]

    const int tid  = threadIdx.x;
    const int lane = tid & 63;
    const int wave = tid >> 6;
    const int lq   = lane >> 4;
    const int ln   = lane & 15;

    const int bi   = blockIdx.x;
    const int b    = bi & 7;            // XCD-pinned batch
    const int rest = bi >> 3;           // 0..255
    const int ho   = (rest >> 3) * 4;   // row-quad base (32 groups)
    const int x0b  = (rest & 7) * 16;   // col-sixteenth base (8 groups)

    const int wrow = wave;              // 0..3: output row ho+wrow
    const int yo   = ho + wrow;         // this wave's output row
    const int pxw  = ln;                // px within 16-col tile
    const int wo   = x0b + pxw;         // this lane's output x

    const _Float16* __restrict__ xbT = xT + (size_t)b * HW_ * 64;

    // ---------------- Stage window (ZERO-padded): rows ho-3..ho+7, ---------
    // cols x0b-3..x0b+18.  11*22*8 = 1936 chunk-slots.
#pragma unroll
    for (int it = 0; it < 8; ++it) {
        const int e = it * 256 + tid;
        if (e < WROWS * WCOLS * 8) {
            const int r   = e / (WCOLS * 8);
            const int rem = e - r * (WCOLS * 8);
            const int cx  = rem >> 3;
            const int q   = rem & 7;
            const int yr  = ho - 3 + r;
            const int xc  = x0b - 3 + cx;
            f16x8 v = splat8((_Float16)0.0f);
            if (((unsigned)yr < H_) && ((unsigned)xc < W_))
                v = *(const f16x8*)&xbT[((size_t)(yr * W_ + xc)) * 64 + q * 8];
            *(f16x8*)&win[(r * WCOLS + cx) * 64 + ((q ^ (cx & 7)) * 8)] = v;
        }
    }
    __syncthreads();

    // ---------------- Phase A: offset/modulator conv via MFMA (no branches)
    f32x4 accA[2];
#pragma unroll
    for (int mt = 0; mt < 2; ++mt) accA[mt] = (f32x4){0.f, 0.f, 0.f, 0.f};

#pragma unroll
    for (int s = 0; s < 18; ++s) {
        const int k = s >> 1, h = s & 1;
        const int ki = k / 3, kj = k - ki * 3;
        f16x8 afA[2];
#pragma unroll
        for (int mt = 0; mt < 2; ++mt)
            afA[mt] = *(const f16x8*)&wpA[(size_t)((s * 2 + mt) * 64 + lane) * 8];
        const int sy = wrow + ki + 2;        // row (yo-1+ki) rel to ho-3
        const int sx = pxw + kj + 2;         // col (wo-1+kj) rel to x0b-3
        const int chunk = h * 4 + lq;
        const f16x8 bfA = *(const f16x8*)&win[(sy * WCOLS + sx) * 64 + ((chunk ^ (sx & 7)) * 8)];
#pragma unroll
        for (int mt = 0; mt < 2; ++mt)
            accA[mt] = __builtin_amdgcn_mfma_f32_16x16x32_f16(afA[mt], bfA, accA[mt], 0, 0, 0);
    }

    // Epilogue A: lane (lq,ln) owns t = mt*16 + lq*4 + r for px ln.
    // Write straight to the params LDS (intra-wave producer/consumer; the
    // compiler's lgkmcnt tracking orders writes before the phase-B reads —
    // no barrier needed, all traffic stays inside wave wrow's slice).
#pragma unroll
    for (int mt = 0; mt < 2; ++mt)
#pragma unroll
        for (int r = 0; r < 4; ++r) {
            const int t = mt * 16 + lq * 4 + r;
            const float val = accA[mt][r];
            if (t < 18)      params[wrow][ln][t] = val + offb[t];
            else if (t < 27) params[wrow][ln][t] = 2.0f / (1.0f + expf(-(val + modb[t - 18])));
        }

    // ---------------- Phase B: deformable gather (LDS) + MFMA --------------
    f32x4 acc[4];
#pragma unroll
    for (int mt = 0; mt < 4; ++mt) acc[mt] = (f32x4){0.f, 0.f, 0.f, 0.f};

#pragma unroll
    for (int k = 0; k < 9; ++k) {
        const int ki = k / 3, kj = k - ki * 3;

        // own-px params at compile-time-constant LDS offsets (broadcast read)
        const float dy = params[wrow][ln][2 * k];
        const float dx = params[wrow][ln][2 * k + 1];
        const float mk = params[wrow][ln][18 + k];

        const float ys = (float)(yo - 1 + ki) + dy;
        const float xs = (float)(wo - 1 + kj) + dx;
        const float y0f = floorf(ys), x0f = floorf(xs);
        const float wy = ys - y0f, wx = xs - x0f;
        const int y0 = (int)y0f, x0 = (int)x0f;
        const float wyc = 1.0f - wy, wxc = 1.0f - wx;
        const float w00 = wyc * wxc * mk;
        const float w01 = wyc * wx  * mk;
        const float w10 = wy  * wxc * mk;
        const float w11 = wy  * wx  * mk;

        // window slots from RAW coords (zero-pad makes raw lookup correct)
        const int sy0 = y0 - ho + 3, sy1 = sy0 + 1;
        const int sx0 = x0 - x0b + 3, sx1 = sx0 + 1;
        const int ok00 = ((unsigned)sy0 < WROWS) & ((unsigned)sx0 < WCOLS);
        const int ok01 = ((unsigned)sy0 < WROWS) & ((unsigned)sx1 < WCOLS);
        const int ok10 = ((unsigned)sy1 < WROWS) & ((unsigned)sx0 < WCOLS);
        const int ok11 = ((unsigned)sy1 < WROWS) & ((unsigned)sx1 < WCOLS);
        const int okk  = ok00 | (ok01 << 1) | (ok10 << 2) | (ok11 << 3);
        // safe (in-window) slots for the LDS address; fallback overrides
        const int cy0 = min(max(sy0, 0), WROWS - 1), cy1 = min(max(sy1, 0), WROWS - 1);
        const int cx0 = min(max(sx0, 0), WCOLS - 1), cx1 = min(max(sx1, 0), WCOLS - 1);
        const int b00 = (cy0 * WCOLS + cx0) * 64, x7_00 = cx0 & 7;
        const int b01 = (cy0 * WCOLS + cx1) * 64, x7_01 = cx1 & 7;
        const int b10 = (cy1 * WCOLS + cx0) * 64, x7_10 = cx0 & 7;
        const int b11 = (cy1 * WCOLS + cx1) * 64, x7_11 = cx1 & 7;

        const f16x8 w00v = splat8((_Float16)w00);
        const f16x8 w01v = splat8((_Float16)w01);
        const f16x8 w10v = splat8((_Float16)w10);
        const f16x8 w11v = splat8((_Float16)w11);

#pragma unroll
        for (int h = 0; h < 2; ++h) {
            const int s = 2 * k + h;
            const int chunk = h * 4 + lq;
            const int c0 = h * 32 + lq * 8;

            f16x8 af[4];
#pragma unroll
            for (int mt = 0; mt < 4; ++mt)
                af[mt] = *(const f16x8*)&wpM[(size_t)((s * 4 + mt) * 64 + lane) * 8];

            f16x8 a00 = *(const f16x8*)&win[b00 + ((chunk ^ x7_00) * 8)];
            f16x8 a01 = *(const f16x8*)&win[b01 + ((chunk ^ x7_01) * 8)];
            f16x8 a10 = *(const f16x8*)&win[b10 + ((chunk ^ x7_10) * 8)];
            f16x8 a11 = *(const f16x8*)&win[b11 + ((chunk ^ x7_11) * 8)];

            // rare fallback: corner outside window (value zeroed if off-image)
            if (__builtin_expect(okk != 15, 0)) {
                if (!ok00) {
                    const int yc = min(max(y0, 0), H_ - 1), xc = min(max(x0, 0), W_ - 1);
                    const bool in = ((unsigned)y0 < H_) && ((unsigned)x0 < W_);
                    a00 = in ? *(const f16x8*)&xbT[((size_t)(yc * W_ + xc)) * 64 + c0] : splat8((_Float16)0.0f);
                }
                if (!ok01) {
                    const int yc = min(max(y0, 0), H_ - 1), xc = min(max(x0 + 1, 0), W_ - 1);
                    const bool in = ((unsigned)y0 < H_) && ((unsigned)(x0 + 1) < W_);
                    a01 = in ? *(const f16x8*)&xbT[((size_t)(yc * W_ + xc)) * 64 + c0] : splat8((_Float16)0.0f);
                }
                if (!ok10) {
                    const int yc = min(max(y0 + 1, 0), H_ - 1), xc = min(max(x0, 0), W_ - 1);
                    const bool in = ((unsigned)(y0 + 1) < H_) && ((unsigned)x0 < W_);
                    a10 = in ? *(const f16x8*)&xbT[((size_t)(yc * W_ + xc)) * 64 + c0] : splat8((_Float16)0.0f);
                }
                if (!ok11) {
                    const int yc = min(max(y0 + 1, 0), H_ - 1), xc = min(max(x0 + 1, 0), W_ - 1);
                    const bool in = ((unsigned)(y0 + 1) < H_) && ((unsigned)(x0 + 1) < W_);
                    a11 = in ? *(const f16x8*)&xbT[((size_t)(yc * W_ + xc)) * 64 + c0] : splat8((_Float16)0.0f);
                }
            }

            f16x8 r = a00 * w00v;
            r = a01 * w01v + r;
            r = a10 * w10v + r;
            r = a11 * w11v + r;

#pragma unroll
            for (int mt = 0; mt < 4; ++mt)
                acc[mt] = __builtin_amdgcn_mfma_f32_16x16x32_f16(af[mt], r, acc[mt], 0, 0, 0);
        }
    }

    // Epilogue B: D col = ln -> px, row = o.
    float* __restrict__ ob = out + (size_t)b * O_ * HW_ + (size_t)yo * W_;
#pragma unroll
    for (int mt = 0; mt < 4; ++mt)
#pragma unroll
        for (int r = 0; r < 4; ++r) {
            const int o = mt * 16 + lq * 4 + r;
            ob[(size_t)o * HW_ + wo] = acc[mt][r];
        }
}

extern "C" void kernel_launch(void* const* d_in, const int* in_sizes, int n_in,
                              void* d_out, int out_size, void* d_ws, size_t ws_size,
                              hipStream_t stream) {
    (void)in_sizes; (void)n_in; (void)out_size; (void)ws_size;
    const float* x    = (const float*)d_in[0];
    const float* offw = (const float*)d_in[1];
    const float* offb = (const float*)d_in[2];
    const float* modw = (const float*)d_in[3];
    const float* modb = (const float*)d_in[4];
    const float* wgt  = (const float*)d_in[5];
    float* out = (float*)d_out;

    _Float16* wpM = (_Float16*)d_ws;                                   // 73728 B
    _Float16* wpA = (_Float16*)((char*)d_ws + WPM_BYTES);              // 36864 B
    _Float16* xT  = (_Float16*)((char*)d_ws + WPM_BYTES + WPA_BYTES);  // 16.78 MB

    prep_kernel<<<TB2_ + 27, 256, 0, stream>>>(x, offw, modw, wgt, xT, wpM, wpA);
    dcn_main_kernel<<<B_ * H_ * 2, 256, 0, stream>>>(xT, wpA, wpM, offb, modb, out);
}